// Round 6
// baseline (685.685 us; speedup 1.0000x reference)
//
#include <hip/hip_runtime.h>

// DIAGNOSTIC round: chunked-scan algebra in pure fp32 VALU (no MFMA, no fp16,
// no swizzle). Decisively splits r5's failure between {algebra/prep/scan}
// (shared with this kernel) and {fp16/swizzle/MFMA mechanics} (absent here).
//
//   t = 64c + tau;  B[c][n] = sum_j w^{63-j} u[64c+j]   (Horner)
//   X[c+1] = w^64 X[c] + B[c],  X[0] = 0                 (fp32 scan)
//   y[64c+tau] = sum_n Re(2Ct_n w^{tau+1} X_n[c])        (carry)
//              + sum_{s<=tau} K[tau-s] u[64c+s]          (local)
//              + D u,  masked t < length[b]
//   K[l] = Re(sum_n 2Ct_n w^l)

#define B_SZ 16
#define H_SZ 256
#define L_SZ 4096

// LDS layout (bytes)
#define O_BR 0          // f32 [64][64]  B real  (overwritten by X real in scan)
#define O_BI 16384      // f32 [64][64]  B imag  (overwritten by X imag)
#define O_GR 32768      // f32 [64][66]  G[tau][n] =  Re(2Ct w^{tau+1})
#define O_GM 49664      // f32 [64][66]            = -Im(2Ct w^{tau+1})
#define O_K  66560      // f32 [64]      K[l]
#define LDS_TOTAL 66816

__global__ __launch_bounds__(256) void dssm_valu(
    const float* __restrict__ u,
    const float* __restrict__ log_dt,
    const float* __restrict__ Cin,
    const float* __restrict__ log_A_real,
    const float* __restrict__ A_imag,
    const float* __restrict__ Dvec,
    const int* __restrict__ length,
    float* __restrict__ y)
{
  extern __shared__ char smem[];
  float* sBr = (float*)(smem + O_BR);
  float* sBi = (float*)(smem + O_BI);
  float* sGr = (float*)(smem + O_GR);
  float* sGm = (float*)(smem + O_GM);
  float* sK  = (float*)(smem + O_K);

  const int tid = threadIdx.x;
  const int l = tid & 63;          // lane: mode n in P1-P3, tau in P4
  const int wv = tid >> 6;
  const int h = blockIdx.x & 255;
  const int b = blockIdx.x >> 8;
  const size_t base = ((size_t)b * H_SZ + h) * L_SZ;
  const float* up = u + base;

  // ---- per-lane mode params (mode n = l) -- identical formulas to r2 (passed) ----
  const float dt = expf(log_dt[h]);
  const float ar = expf(log_A_real[h * 64 + l]);     // A = -ar + i*ai
  const float ai = A_imag[h * 64 + l];
  const float er = expf(-ar * dt);
  const float th = ai * dt;
  const float wr = er * cosf(th), wi = er * sinf(th); // w = exp(dt*A)
  const float em1r = wr - 1.0f, em1i = wi;
  const float inv = 1.0f / (ar * ar + ai * ai);
  const float qr = (em1i * ai - em1r * ar) * inv;     // (w-1)/A
  const float qi = -(em1r * ai + em1i * ar) * inv;
  const float c0 = Cin[(h * 64 + l) * 2 + 0];
  const float c1 = Cin[(h * 64 + l) * 2 + 1];
  const float c2r = 2.0f * (c0 * qr - c1 * qi);       // 2*Ct
  const float c2i = 2.0f * (c0 * qi + c1 * qr);

  const float w2r = wr*wr - wi*wi,     w2i = 2.f*wr*wi;
  const float w4r = w2r*w2r - w2i*w2i, w4i = 2.f*w2r*w2i;
  const float w8r = w4r*w4r - w4i*w4i, w8i = 2.f*w4r*w4i;
  const float w16r= w8r*w8r - w8i*w8i, w16i= 2.f*w8r*w8i;

  // base = w^{16*wv} (wave-uniform loop count)
  float b0r = 1.f, b0i = 0.f;
  for (int s2 = 0; s2 < wv; ++s2) {
    const float nr = b0r*w16r - b0i*w16i, ni = b0r*w16i + b0i*w16r;
    b0r = nr; b0i = ni;
  }

  // ---- P1: B[c][n] via Horner; wave wv owns chunks 16wv..16wv+15 ----
  for (int cc = 0; cc < 16; ++cc) {
    const int c = 16*wv + cc;
    const float* uc = up + c*64;
    float hr_ = 0.f, hi_ = 0.f;
    #pragma unroll
    for (int j = 0; j < 64; ++j) {          // B = (((u0*w+u1)*w+u2)...)
      const float uj = uc[j];
      const float nr = fmaf(wr, hr_, fmaf(-wi, hi_, uj));
      const float ni = fmaf(wi, hr_, wr * hi_);
      hr_ = nr; hi_ = ni;
    }
    sBr[c*64 + l] = hr_;
    sBi[c*64 + l] = hi_;
  }

  // ---- P2a: K[k] for k = 16wv..16wv+15 ----
  {
    float pr = b0r, pi = b0i;                // w^k
    for (int kk = 0; kk < 16; ++kk) {
      const int k = 16*wv + kk;
      const float gre = c2r*pr - c2i*pi;     // Re(2Ct w^k), per mode
      float s = gre;
      #pragma unroll
      for (int m = 1; m < 64; m <<= 1) s += __shfl_xor(s, m, 64);
      if (l == 0) sK[k] = s;
      const float nr = pr*wr - pi*wi, ni = pr*wi + pi*wr;
      pr = nr; pi = ni;
    }
  }
  // ---- P2b: G rows 16wv..16wv+15: G[row][n] = 2Ct_n w^{row+1} ----
  {
    float pr = b0r*wr - b0i*wi, pi = b0r*wi + b0i*wr;   // w^{16wv+1}
    for (int rr = 0; rr < 16; ++rr) {
      const int row = 16*wv + rr;
      const float gre = c2r*pr - c2i*pi;
      const float gim = c2r*pi + c2i*pr;
      sGr[row*66 + l] =  gre;
      sGm[row*66 + l] = -gim;
      const float nr = pr*wr - pi*wi, ni = pr*wi + pi*wr;
      pr = nr; pi = ni;
    }
  }
  __syncthreads();

  // ---- P3: serial chunk scan (wave 0); X[c] = pre-state, overwrites B ----
  if (wv == 0) {
    const float l2r = w16r*w16r - w16i*w16i, l2i = 2.f*w16r*w16i; // w^32
    const float lr  = l2r*l2r - l2i*l2i,     li  = 2.f*l2r*l2i;   // w^64
    float xr = 0.f, xi = 0.f;
    for (int c = 0; c < 64; ++c) {
      const float br = sBr[c*64 + l];        // read B first
      const float bi = sBi[c*64 + l];
      sBr[c*64 + l] = xr;                    // then store X[c] (pre-update)
      sBi[c*64 + l] = xi;
      const float nr = fmaf(lr, xr, fmaf(-li, xi, br));
      const float ni = fmaf(lr, xi, fmaf(li, xr, bi));
      xr = nr; xi = ni;
    }
  }
  __syncthreads();

  // ---- P4: outputs; wave wv owns chunks 16wv..16wv+15, lane = tau ----
  const float Dh = Dvec[h];
  const int len = length[b];
  float* yp = y + base;
  for (int cc = 0; cc < 16; ++cc) {
    const int c = 16*wv + cc;
    const float* uc = up + c*64;
    float acc = 0.f;
    // carry: sum_n Xr[c][n]*Gr[tau][n] + Xi[c][n]*Gm[tau][n]
    #pragma unroll 8
    for (int n = 0; n < 64; ++n) {
      acc = fmaf(sBr[c*64 + n], sGr[l*66 + n], acc);   // sBr/sBi now hold X
      acc = fmaf(sBi[c*64 + n], sGm[l*66 + n], acc);
    }
    // local causal conv: sum_{s<=tau} K[tau-s] * u_c[s]
    #pragma unroll 8
    for (int s = 0; s < 64; ++s) {
      const int idx = l - s;
      float kv = 0.f;
      if (idx >= 0) kv = sK[idx];
      acc = fmaf(kv, uc[s], acc);
    }
    const int t = c*64 + l;
    const float out = fmaf(Dh, uc[l], acc);
    yp[t] = (t < len) ? out : 0.f;
  }
}

extern "C" void kernel_launch(void* const* d_in, const int* in_sizes, int n_in,
                              void* d_out, int out_size, void* d_ws, size_t ws_size,
                              hipStream_t stream) {
  const float* u          = (const float*)d_in[0];
  const float* log_dt     = (const float*)d_in[1];
  const float* C          = (const float*)d_in[2];
  const float* log_A_real = (const float*)d_in[3];
  const float* A_imag     = (const float*)d_in[4];
  const float* D          = (const float*)d_in[5];
  const int*   length     = (const int*)d_in[6];
  float* y = (float*)d_out;

  dssm_valu<<<B_SZ * H_SZ, 256, LDS_TOTAL, stream>>>(
      u, log_dt, C, log_A_real, A_imag, D, length, y);
}

// Round 7
// 601.917 us; speedup vs baseline: 1.1392x; 1.1392x over previous
//
#include <hip/hip_runtime.h>

// BISECT round: r6's proven fp32 scaffold + ONLY the MFMA B-GEMM grafted in.
//   B[c][n] = sum_j w^{63-j} u[64c+j]  via mfma_f32_16x16x32_f16
//     (U, V staged fp16 in XOR-swizzled LDS; accum fp32; B written fp32)
//   everything else (scan, G/K build, carry/local sums, epilogue) = r6 verbatim.
// Single changed variable vs r6 => failure isolates the B-GEMM mechanics
// {U staging swizzle, V build swizzle, frag reads, MFMA wrapper, C/D write}.

#define B_SZ 16
#define H_SZ 256
#define L_SZ 4096

using s16x8 = __attribute__((ext_vector_type(8))) short;
using h16x8 = __attribute__((ext_vector_type(8))) _Float16;
using f32x4 = __attribute__((ext_vector_type(4))) float;

template <typename T>
__device__ inline auto mfma_try(T a, T b, f32x4 c, int)
    -> decltype(__builtin_amdgcn_mfma_f32_16x16x32_f16(a, b, c, 0, 0, 0)) {
  return __builtin_amdgcn_mfma_f32_16x16x32_f16(a, b, c, 0, 0, 0);
}
template <typename T>
__device__ inline f32x4 mfma_try(T a, T b, f32x4 c, long) {
  return __builtin_amdgcn_mfma_f32_16x16x32_f16(
      __builtin_bit_cast(h16x8, a), __builtin_bit_cast(h16x8, b), c, 0, 0, 0);
}
__device__ inline f32x4 MFMA(s16x8 a, s16x8 b, f32x4 c) {
  return mfma_try(a, b, c, 0);
}

__device__ inline unsigned short f2h(float f) {
  return __builtin_bit_cast(unsigned short, (_Float16)f);   // RNE
}

// LDS layout (bytes)
#define O_U   0          // fp16 [64][64] swizzled          (dead after B-GEMM)
#define O_VR  8192       // fp16 [64][64] swizzled          (dead after B-GEMM)
#define O_VI  16384      // fp16 [64][64] swizzled          (dead after B-GEMM)
#define O_BR  24576      // f32 [64][64]  B real -> X real (in-place scan)
#define O_BI  40960      // f32 [64][64]  B imag -> X imag
#define O_GR  57344      // f32 [64][66]  G[tau][n] =  Re(2Ct w^{tau+1})
#define O_GM  0          // f32 [64][66]            = -Im(...)  over dead U/VR/VI
#define O_K   74240      // f32 [64]
#define LDS_TOTAL 74496

__global__ __launch_bounds__(256) void dssm_bisect(
    const float* __restrict__ u,
    const float* __restrict__ log_dt,
    const float* __restrict__ Cin,
    const float* __restrict__ log_A_real,
    const float* __restrict__ A_imag,
    const float* __restrict__ Dvec,
    const int* __restrict__ length,
    float* __restrict__ y)
{
  extern __shared__ char smem[];
  float* sBr = (float*)(smem + O_BR);
  float* sBi = (float*)(smem + O_BI);
  float* sGr = (float*)(smem + O_GR);
  float* sGm = (float*)(smem + O_GM);
  float* sK  = (float*)(smem + O_K);

  const int tid = threadIdx.x;
  const int l = tid & 63;
  const int wv = tid >> 6;
  const int h = blockIdx.x & 255;
  const int b = blockIdx.x >> 8;
  const size_t base = ((size_t)b * H_SZ + h) * L_SZ;
  const float* up = u + base;

  // ---- per-lane mode params (r6 verbatim) ----
  const float dt = expf(log_dt[h]);
  const float ar = expf(log_A_real[h * 64 + l]);
  const float ai = A_imag[h * 64 + l];
  const float er = expf(-ar * dt);
  const float th = ai * dt;
  const float wr = er * cosf(th), wi = er * sinf(th);
  const float em1r = wr - 1.0f, em1i = wi;
  const float inv = 1.0f / (ar * ar + ai * ai);
  const float qr = (em1i * ai - em1r * ar) * inv;
  const float qi = -(em1r * ai + em1i * ar) * inv;
  const float c0 = Cin[(h * 64 + l) * 2 + 0];
  const float c1 = Cin[(h * 64 + l) * 2 + 1];
  const float c2r = 2.0f * (c0 * qr - c1 * qi);
  const float c2i = 2.0f * (c0 * qi + c1 * qr);

  const float w2r = wr*wr - wi*wi,     w2i = 2.f*wr*wi;
  const float w4r = w2r*w2r - w2i*w2i, w4i = 2.f*w2r*w2i;
  const float w8r = w4r*w4r - w4i*w4i, w8i = 2.f*w4r*w4i;
  const float w16r= w8r*w8r - w8i*w8i, w16i= 2.f*w8r*w8i;

  float b0r = 1.f, b0i = 0.f;                 // w^{16*wv}
  for (int s2 = 0; s2 < wv; ++s2) {
    const float nr = b0r*w16r - b0i*w16i, ni = b0r*w16i + b0i*w16r;
    b0r = nr; b0i = ni;
  }

  // ---- phase A: stage U (fp32 -> fp16, XOR-swizzled [64][64]) [r5 verbatim] ----
  {
    const int e0 = tid * 16;
    const float4 f0 = *(const float4*)(up + e0);
    const float4 f1 = *(const float4*)(up + e0 + 4);
    const float4 f2 = *(const float4*)(up + e0 + 8);
    const float4 f3 = *(const float4*)(up + e0 + 12);
    s16x8 v0, v1;
    v0[0]=(short)f2h(f0.x); v0[1]=(short)f2h(f0.y);
    v0[2]=(short)f2h(f0.z); v0[3]=(short)f2h(f0.w);
    v0[4]=(short)f2h(f1.x); v0[5]=(short)f2h(f1.y);
    v0[6]=(short)f2h(f1.z); v0[7]=(short)f2h(f1.w);
    v1[0]=(short)f2h(f2.x); v1[1]=(short)f2h(f2.y);
    v1[2]=(short)f2h(f2.z); v1[3]=(short)f2h(f2.w);
    v1[4]=(short)f2h(f3.x); v1[5]=(short)f2h(f3.y);
    v1[6]=(short)f2h(f3.z); v1[7]=(short)f2h(f3.w);
    const int r = tid >> 2;
    const int q0 = (2 * tid) & 7;
    char* ub = smem + O_U + r * 128;
    *(s16x8*)(ub + (((q0    ) ^ (r & 7)) << 4)) = v0;
    *(s16x8*)(ub + (((q0 + 1) ^ (r & 7)) << 4)) = v1;
  }
  // ---- phase V: build V fp16 swizzled; V[n=l][63-k] = w^k [r5 verbatim] ----
  {
    float pr = b0r, pi = b0i;
    #pragma unroll
    for (int kk = 0; kk < 16; ++kk) {
      const int k = wv * 16 + kk;
      const int c63 = 63 - k;
      const int vb = l * 128 + (((c63 >> 3) ^ (l & 7)) << 4) + (c63 & 7) * 2;
      *(unsigned short*)(smem + O_VR + vb) = f2h(pr);
      *(unsigned short*)(smem + O_VI + vb) = f2h(pi);
      const float nr = pr*wr - pi*wi, ni = pr*wi + pi*wr;
      pr = nr; pi = ni;
    }
  }
  __syncthreads();

  // ---- B-GEMM: B = U . V^T via MFMA (fp32 accum, fp32 B write) ----
  {
    auto frag = [&](int base_, int row, int kc) -> s16x8 {
      return *(const s16x8*)(smem + base_ + row * 128 + ((kc ^ (row & 7)) << 4));
    };
    const int arow = 16 * wv + (l & 15);
    const int kq = l >> 4;
    const s16x8 aU0 = frag(O_U, arow, kq);
    const s16x8 aU1 = frag(O_U, arow, 4 + kq);

    f32x4 accR[4], accI[4];
    #pragma unroll
    for (int j = 0; j < 4; ++j) { accR[j] = f32x4{0,0,0,0}; accI[j] = f32x4{0,0,0,0}; }
    #pragma unroll
    for (int j = 0; j < 4; ++j) {
      const int bcol = 16 * j + (l & 15);
      accR[j] = MFMA(aU0, frag(O_VR, bcol, kq),     accR[j]);
      accR[j] = MFMA(aU1, frag(O_VR, bcol, 4 + kq), accR[j]);
      accI[j] = MFMA(aU0, frag(O_VI, bcol, kq),     accI[j]);
      accI[j] = MFMA(aU1, frag(O_VI, bcol, 4 + kq), accI[j]);
    }
    #pragma unroll
    for (int j = 0; j < 4; ++j) {
      const int n = 16 * j + (l & 15);
      #pragma unroll
      for (int r = 0; r < 4; ++r) {
        const int c = 16 * wv + (l >> 4) * 4 + r;   // C/D: row=(l>>4)*4+r, col=l&15
        sBr[c * 64 + n] = accR[j][r];
        sBi[c * 64 + n] = accI[j][r];
      }
    }
  }
  __syncthreads();   // U/VR/VI dead from here; sGm overlays them

  // ---- G/K build fp32 (r6 P2a/P2b; new bases) ----
  {
    float pr = b0r, pi = b0i;                // w^k
    for (int kk = 0; kk < 16; ++kk) {
      const int k = 16*wv + kk;
      const float gre = c2r*pr - c2i*pi;
      float s = gre;
      #pragma unroll
      for (int m = 1; m < 64; m <<= 1) s += __shfl_xor(s, m, 64);
      if (l == 0) sK[k] = s;
      const float nr = pr*wr - pi*wi, ni = pr*wi + pi*wr;
      pr = nr; pi = ni;
    }
  }
  {
    float pr = b0r*wr - b0i*wi, pi = b0r*wi + b0i*wr;   // w^{16wv+1}
    for (int rr = 0; rr < 16; ++rr) {
      const int row = 16*wv + rr;
      const float gre = c2r*pr - c2i*pi;
      const float gim = c2r*pi + c2i*pr;
      sGr[row*66 + l] =  gre;
      sGm[row*66 + l] = -gim;
      const float nr = pr*wr - pi*wi, ni = pr*wi + pi*wr;
      pr = nr; pi = ni;
    }
  }
  __syncthreads();

  // ---- serial chunk scan (wave 0), in-place B -> X [r6 verbatim] ----
  if (wv == 0) {
    const float l2r = w16r*w16r - w16i*w16i, l2i = 2.f*w16r*w16i; // w^32
    const float lr  = l2r*l2r - l2i*l2i,     li  = 2.f*l2r*l2i;   // w^64
    float xr = 0.f, xi = 0.f;
    for (int c = 0; c < 64; ++c) {
      const float br = sBr[c*64 + l];
      const float bi = sBi[c*64 + l];
      sBr[c*64 + l] = xr;
      sBi[c*64 + l] = xi;
      const float nr = fmaf(lr, xr, fmaf(-li, xi, br));
      const float ni = fmaf(lr, xi, fmaf(li, xr, bi));
      xr = nr; xi = ni;
    }
  }
  __syncthreads();

  // ---- P4: outputs (r6 verbatim) ----
  const float Dh = Dvec[h];
  const int len = length[b];
  float* yp = y + base;
  for (int cc = 0; cc < 16; ++cc) {
    const int c = 16*wv + cc;
    const float* uc = up + c*64;
    float acc = 0.f;
    #pragma unroll 8
    for (int n = 0; n < 64; ++n) {
      acc = fmaf(sBr[c*64 + n], sGr[l*66 + n], acc);
      acc = fmaf(sBi[c*64 + n], sGm[l*66 + n], acc);
    }
    #pragma unroll 8
    for (int s = 0; s < 64; ++s) {
      const int idx = l - s;
      float kv = 0.f;
      if (idx >= 0) kv = sK[idx];
      acc = fmaf(kv, uc[s], acc);
    }
    const int t = c*64 + l;
    const float out = fmaf(Dh, uc[l], acc);
    yp[t] = (t < len) ? out : 0.f;
  }
}

extern "C" void kernel_launch(void* const* d_in, const int* in_sizes, int n_in,
                              void* d_out, int out_size, void* d_ws, size_t ws_size,
                              hipStream_t stream) {
  const float* u          = (const float*)d_in[0];
  const float* log_dt     = (const float*)d_in[1];
  const float* C          = (const float*)d_in[2];
  const float* log_A_real = (const float*)d_in[3];
  const float* A_imag     = (const float*)d_in[4];
  const float* D          = (const float*)d_in[5];
  const int*   length     = (const int*)d_in[6];
  float* y = (float*)d_out;

  dssm_bisect<<<B_SZ * H_SZ, 256, LDS_TOTAL, stream>>>(
      u, log_dt, C, log_A_real, A_imag, D, length, y);
}

// Round 8
// 107.614 us; speedup vs baseline: 6.3717x; 5.5933x over previous
//
#include <hip/hip_runtime.h>

// DSS forward, chunked-parallel scan, all GEMMs on MFMA (fp16 ops, fp32 accum).
// Proven by r6/r7: algebra, prep math, K build, fp32 scan, U/V staging+swizzle,
// frag reads, MFMA wrapper, C/D write mapping, epilogue.
// R8 grafts (vs r7): G fp16 swz build, X fp16 swz stores, Tt fp16 build,
// phase-3 MFMA carry+local. Avoids (untested, r5-only): B fp16 LDS packing,
// SCR_K/SCR_LAM overlay under the scan's X region. B stays fp32; lambda=w^64
// recomputed in-register; sK parked in the (later-clobbered) B region.

#define B_SZ 16
#define H_SZ 256
#define L_SZ 4096

using s16x8 = __attribute__((ext_vector_type(8))) short;
using h16x8 = __attribute__((ext_vector_type(8))) _Float16;
using f32x4 = __attribute__((ext_vector_type(4))) float;

template <typename T>
__device__ inline auto mfma_try(T a, T b, f32x4 c, int)
    -> decltype(__builtin_amdgcn_mfma_f32_16x16x32_f16(a, b, c, 0, 0, 0)) {
  return __builtin_amdgcn_mfma_f32_16x16x32_f16(a, b, c, 0, 0, 0);
}
template <typename T>
__device__ inline f32x4 mfma_try(T a, T b, f32x4 c, long) {
  return __builtin_amdgcn_mfma_f32_16x16x32_f16(
      __builtin_bit_cast(h16x8, a), __builtin_bit_cast(h16x8, b), c, 0, 0, 0);
}
__device__ inline f32x4 MFMA(s16x8 a, s16x8 b, f32x4 c) {
  return mfma_try(a, b, c, 0);
}

__device__ inline unsigned short f2h(float f) {
  return __builtin_bit_cast(unsigned short, (_Float16)f);   // RNE
}

// ---- LDS map (80 KB exactly -> 2 blocks/CU) ----
#define O_U   0          // fp16 [64][64] swz; alive through phase 3
#define O_VR  8192       // fp16 [64][64] swz; dead after B-GEMM -> X real
#define O_VI  16384      // fp16 [64][64] swz; dead after B-GEMM -> X imag
#define O_XR  O_VR
#define O_XI  O_VI
#define O_TT  24576      // fp16 [64][64] swz: Tt[tau][s] = K[tau-s]
#define O_GR  32768      // fp16 [64][64] swz: G[tau][n] =  Re(2Ct w^{tau+1})
#define O_GM  40960      // fp16 [64][64] swz:            = -Im(2Ct w^{tau+1})
#define O_BR  49152      // f32 [64][64] B real -> X pre-states (in-place scan)
#define O_BI  65536      // f32 [64][64] B imag
#define O_K   O_BR       // f32[64] K; dead before B-GEMM writes O_BR
#define LDS_TOTAL 81920

__global__ __launch_bounds__(256) void dssm_mfma(
    const float* __restrict__ u,
    const float* __restrict__ log_dt,
    const float* __restrict__ Cin,
    const float* __restrict__ log_A_real,
    const float* __restrict__ A_imag,
    const float* __restrict__ Dvec,
    const int* __restrict__ length,
    float* __restrict__ y)
{
  extern __shared__ char smem[];
  float* sBr = (float*)(smem + O_BR);
  float* sBi = (float*)(smem + O_BI);
  float* sK  = (float*)(smem + O_K);

  const int tid = threadIdx.x;
  const int l = tid & 63;
  const int wv = tid >> 6;
  const int h = blockIdx.x & 255;
  const int b = blockIdx.x >> 8;
  const size_t base = ((size_t)b * H_SZ + h) * L_SZ;
  const float* up = u + base;

  // ---- per-lane mode params (r6/r7 verbatim) ----
  const float dt = expf(log_dt[h]);
  const float ar = expf(log_A_real[h * 64 + l]);
  const float ai = A_imag[h * 64 + l];
  const float er = expf(-ar * dt);
  const float th = ai * dt;
  const float wr = er * cosf(th), wi = er * sinf(th);
  const float em1r = wr - 1.0f, em1i = wi;
  const float inv = 1.0f / (ar * ar + ai * ai);
  const float qr = (em1i * ai - em1r * ar) * inv;
  const float qi = -(em1r * ai + em1i * ar) * inv;
  const float c0 = Cin[(h * 64 + l) * 2 + 0];
  const float c1 = Cin[(h * 64 + l) * 2 + 1];
  const float c2r = 2.0f * (c0 * qr - c1 * qi);
  const float c2i = 2.0f * (c0 * qi + c1 * qr);

  const float w2r = wr*wr - wi*wi,     w2i = 2.f*wr*wi;
  const float w4r = w2r*w2r - w2i*w2i, w4i = 2.f*w2r*w2i;
  const float w8r = w4r*w4r - w4i*w4i, w8i = 2.f*w4r*w4i;
  const float w16r= w8r*w8r - w8i*w8i, w16i= 2.f*w8r*w8i;

  float b0r = 1.f, b0i = 0.f;                 // w^{16*wv}
  for (int s2 = 0; s2 < wv; ++s2) {
    const float nr = b0r*w16r - b0i*w16i, ni = b0r*w16i + b0i*w16r;
    b0r = nr; b0i = ni;
  }

  // ---- phase A: stage U (fp32 -> fp16, XOR-swizzled) [r7 verbatim] ----
  {
    const int e0 = tid * 16;
    const float4 f0 = *(const float4*)(up + e0);
    const float4 f1 = *(const float4*)(up + e0 + 4);
    const float4 f2 = *(const float4*)(up + e0 + 8);
    const float4 f3 = *(const float4*)(up + e0 + 12);
    s16x8 v0, v1;
    v0[0]=(short)f2h(f0.x); v0[1]=(short)f2h(f0.y);
    v0[2]=(short)f2h(f0.z); v0[3]=(short)f2h(f0.w);
    v0[4]=(short)f2h(f1.x); v0[5]=(short)f2h(f1.y);
    v0[6]=(short)f2h(f1.z); v0[7]=(short)f2h(f1.w);
    v1[0]=(short)f2h(f2.x); v1[1]=(short)f2h(f2.y);
    v1[2]=(short)f2h(f2.z); v1[3]=(short)f2h(f2.w);
    v1[4]=(short)f2h(f3.x); v1[5]=(short)f2h(f3.y);
    v1[6]=(short)f2h(f3.z); v1[7]=(short)f2h(f3.w);
    const int r = tid >> 2;
    const int q0 = (2 * tid) & 7;
    char* ub = smem + O_U + r * 128;
    *(s16x8*)(ub + (((q0    ) ^ (r & 7)) << 4)) = v0;
    *(s16x8*)(ub + (((q0 + 1) ^ (r & 7)) << 4)) = v1;
  }

  // ---- phase V: V[n=l][63-k] = w^k (fp16 swz) [r7 verbatim] ----
  {
    float pr = b0r, pi = b0i;
    #pragma unroll
    for (int kk = 0; kk < 16; ++kk) {
      const int k = wv * 16 + kk;
      const int c63 = 63 - k;
      const int vb = l * 128 + (((c63 >> 3) ^ (l & 7)) << 4) + (c63 & 7) * 2;
      *(unsigned short*)(smem + O_VR + vb) = f2h(pr);
      *(unsigned short*)(smem + O_VI + vb) = f2h(pi);
      const float nr = pr*wr - pi*wi, ni = pr*wi + pi*wr;
      pr = nr; pi = ni;
    }
  }

  // ---- phase G/K: K[k] -> sK (fp32, proven); G rows fp16 swz (GRAFT) ----
  {
    float pr = b0r, pi = b0i;                // w^k
    #pragma unroll
    for (int kk = 0; kk < 16; ++kk) {
      const int k = 16*wv + kk;
      const float gre = c2r*pr - c2i*pi;     // Re(2Ct w^k)
      const float gim = c2r*pi + c2i*pr;
      float s = gre;
      #pragma unroll
      for (int m = 1; m < 64; m <<= 1) s += __shfl_xor(s, m, 64);
      if (l == 0) sK[k] = s;
      if (k >= 1) {                          // G[k-1][n=l] = 2Ct w^k
        const int row = k - 1;
        const int gb = row * 128 + (((l >> 3) ^ (row & 7)) << 4) + (l & 7) * 2;
        *(unsigned short*)(smem + O_GR + gb) = f2h(gre);
        *(unsigned short*)(smem + O_GM + gb) = f2h(-gim);
      }
      const float nr = pr*wr - pi*wi, ni = pr*wi + pi*wr;
      pr = nr; pi = ni;
    }
    if (wv == 3) {                           // row 63: 2Ct w^64
      const float gre = c2r*pr - c2i*pi;
      const float gim = c2r*pi + c2i*pr;
      const int gb = 63 * 128 + (((l >> 3) ^ 7) << 4) + (l & 7) * 2;
      *(unsigned short*)(smem + O_GR + gb) = f2h(gre);
      *(unsigned short*)(smem + O_GM + gb) = f2h(-gim);
    }
  }
  __syncthreads();

  // ---- phase C: Tt[tau][s] = K[tau-s] (fp16 swz) from sK (GRAFT) ----
  {
    const int tau = tid >> 2;
    const int sb = tid & 3;
    #pragma unroll
    for (int half = 0; half < 2; ++half) {
      const int q = sb * 2 + half;
      s16x8 v;
      #pragma unroll
      for (int e = 0; e < 8; ++e) {
        const int s = q * 8 + e;
        float kv = 0.0f;
        if (s <= tau) kv = sK[tau - s];
        v[e] = (short)f2h(kv);
      }
      *(s16x8*)(smem + O_TT + tau * 128 + ((q ^ (tau & 7)) << 4)) = v;
    }
  }
  __syncthreads();

  auto frag = [&](int base_, int row, int kc) -> s16x8 {
    return *(const s16x8*)(smem + base_ + row * 128 + ((kc ^ (row & 7)) << 4));
  };
  const int arow = 16 * wv + (l & 15);
  const int kq = l >> 4;
  const s16x8 aU0 = frag(O_U, arow, kq);
  const s16x8 aU1 = frag(O_U, arow, 4 + kq);

  // ---- B-GEMM: B = U.V^T via MFMA, B written fp32 [r7 verbatim] ----
  {
    f32x4 accR[4], accI[4];
    #pragma unroll
    for (int j = 0; j < 4; ++j) { accR[j] = f32x4{0,0,0,0}; accI[j] = f32x4{0,0,0,0}; }
    #pragma unroll
    for (int j = 0; j < 4; ++j) {
      const int bcol = 16 * j + (l & 15);
      accR[j] = MFMA(aU0, frag(O_VR, bcol, kq),     accR[j]);
      accR[j] = MFMA(aU1, frag(O_VR, bcol, 4 + kq), accR[j]);
      accI[j] = MFMA(aU0, frag(O_VI, bcol, kq),     accI[j]);
      accI[j] = MFMA(aU1, frag(O_VI, bcol, 4 + kq), accI[j]);
    }
    #pragma unroll
    for (int j = 0; j < 4; ++j) {
      const int n = 16 * j + (l & 15);
      #pragma unroll
      for (int r = 0; r < 4; ++r) {
        const int c = 16 * wv + (l >> 4) * 4 + r;
        sBr[c * 64 + n] = accR[j][r];        // clobbers sK (dead)
        sBi[c * 64 + n] = accI[j][r];
      }
    }
  }
  __syncthreads();   // VR/VI dead; scan may overwrite them with X

  // ---- scan (wave 0): fp32 states, X[c]=pre-state stored fp16 swz (GRAFT) ----
  if (wv == 0) {
    const float l2r = w16r*w16r - w16i*w16i, l2i = 2.f*w16r*w16i; // w^32
    const float lr  = l2r*l2r - l2i*l2i,     li  = 2.f*l2r*l2i;   // w^64
    float xr = 0.f, xi = 0.f;
    for (int c = 0; c < 64; ++c) {
      const int xo = c * 128 + (((l >> 3) ^ (c & 7)) << 4) + (l & 7) * 2;
      *(unsigned short*)(smem + O_XR + xo) = f2h(xr);
      *(unsigned short*)(smem + O_XI + xo) = f2h(xi);
      const float br = sBr[c*64 + l];
      const float bi = sBi[c*64 + l];
      const float nr = fmaf(lr, xr, fmaf(-li, xi, br));
      const float ni = fmaf(lr, xi, fmaf(li, xr, bi));
      xr = nr; xi = ni;
    }
  }
  __syncthreads();

  // ---- phase 3: Y = U.Tt^T + Xr.Gr^T + Xi.Gm^T via MFMA (GRAFT) ----
  f32x4 acc[4];
  #pragma unroll
  for (int j = 0; j < 4; ++j) acc[j] = f32x4{0,0,0,0};
  const s16x8 aXr0 = frag(O_XR, arow, kq);
  const s16x8 aXr1 = frag(O_XR, arow, 4 + kq);
  const s16x8 aXi0 = frag(O_XI, arow, kq);
  const s16x8 aXi1 = frag(O_XI, arow, 4 + kq);
  #pragma unroll
  for (int j = 0; j < 4; ++j) {
    const int bcol = 16 * j + (l & 15);
    acc[j] = MFMA(aU0,  frag(O_TT, bcol, kq),     acc[j]);
    acc[j] = MFMA(aU1,  frag(O_TT, bcol, 4 + kq), acc[j]);
    acc[j] = MFMA(aXr0, frag(O_GR, bcol, kq),     acc[j]);
    acc[j] = MFMA(aXr1, frag(O_GR, bcol, 4 + kq), acc[j]);
    acc[j] = MFMA(aXi0, frag(O_GM, bcol, kq),     acc[j]);
    acc[j] = MFMA(aXi1, frag(O_GM, bcol, 4 + kq), acc[j]);
  }

  // ---- epilogue: y = acc + D*u, length mask [r5 mapping == r7-proven] ----
  const float Dh = Dvec[h];
  const int len = length[b];
  float* yp = y + base;
  #pragma unroll
  for (int j = 0; j < 4; ++j) {
    #pragma unroll
    for (int r = 0; r < 4; ++r) {
      const int t = (16 * wv + (l >> 4) * 4 + r) * 64 + 16 * j + (l & 15);
      const float out = fmaf(Dh, up[t], acc[j][r]);
      yp[t] = (t < len) ? out : 0.0f;
    }
  }
}

extern "C" void kernel_launch(void* const* d_in, const int* in_sizes, int n_in,
                              void* d_out, int out_size, void* d_ws, size_t ws_size,
                              hipStream_t stream) {
  const float* u          = (const float*)d_in[0];
  const float* log_dt     = (const float*)d_in[1];
  const float* C          = (const float*)d_in[2];
  const float* log_A_real = (const float*)d_in[3];
  const float* A_imag     = (const float*)d_in[4];
  const float* D          = (const float*)d_in[5];
  const int*   length     = (const int*)d_in[6];
  float* y = (float*)d_out;

  dssm_mfma<<<B_SZ * H_SZ, 256, LDS_TOTAL, stream>>>(
      u, log_dt, C, log_A_real, A_imag, D, length, y);
}

// Round 12
// 107.365 us; speedup vs baseline: 6.3865x; 1.0023x over previous
//
#include <hip/hip_runtime.h>

// ROUND 12: byte-for-byte resubmission of round 8's PASSING kernel (107.6 us)
// as a reproducibility probe. r9/r10/r11 (three distinct restructures) all
// failed with audit-resistant errors (1.49 / 1.93 / 0.546); this determines
// whether r8 is robust (restructures each buggy) or itself timing-flaky
// (latent race in the shared skeleton).
//
// DSS forward, chunked-parallel scan, all GEMMs on MFMA (fp16 ops, fp32 accum).
// Proven by r6/r7: algebra, prep math, K build, fp32 scan, U/V staging+swizzle,
// frag reads, MFMA wrapper, C/D write mapping, epilogue.

#define B_SZ 16
#define H_SZ 256
#define L_SZ 4096

using s16x8 = __attribute__((ext_vector_type(8))) short;
using h16x8 = __attribute__((ext_vector_type(8))) _Float16;
using f32x4 = __attribute__((ext_vector_type(4))) float;

template <typename T>
__device__ inline auto mfma_try(T a, T b, f32x4 c, int)
    -> decltype(__builtin_amdgcn_mfma_f32_16x16x32_f16(a, b, c, 0, 0, 0)) {
  return __builtin_amdgcn_mfma_f32_16x16x32_f16(a, b, c, 0, 0, 0);
}
template <typename T>
__device__ inline f32x4 mfma_try(T a, T b, f32x4 c, long) {
  return __builtin_amdgcn_mfma_f32_16x16x32_f16(
      __builtin_bit_cast(h16x8, a), __builtin_bit_cast(h16x8, b), c, 0, 0, 0);
}
__device__ inline f32x4 MFMA(s16x8 a, s16x8 b, f32x4 c) {
  return mfma_try(a, b, c, 0);
}

__device__ inline unsigned short f2h(float f) {
  return __builtin_bit_cast(unsigned short, (_Float16)f);   // RNE
}

// ---- LDS map (80 KB exactly -> 2 blocks/CU) ----
#define O_U   0          // fp16 [64][64] swz; alive through phase 3
#define O_VR  8192       // fp16 [64][64] swz; dead after B-GEMM -> X real
#define O_VI  16384      // fp16 [64][64] swz; dead after B-GEMM -> X imag
#define O_XR  O_VR
#define O_XI  O_VI
#define O_TT  24576      // fp16 [64][64] swz: Tt[tau][s] = K[tau-s]
#define O_GR  32768      // fp16 [64][64] swz: G[tau][n] =  Re(2Ct w^{tau+1})
#define O_GM  40960      // fp16 [64][64] swz:            = -Im(2Ct w^{tau+1})
#define O_BR  49152      // f32 [64][64] B real -> X pre-states (in-place scan)
#define O_BI  65536      // f32 [64][64] B imag
#define O_K   O_BR       // f32[64] K; dead before B-GEMM clobbers O_BR
#define LDS_TOTAL 81920

__global__ __launch_bounds__(256) void dssm_mfma(
    const float* __restrict__ u,
    const float* __restrict__ log_dt,
    const float* __restrict__ Cin,
    const float* __restrict__ log_A_real,
    const float* __restrict__ A_imag,
    const float* __restrict__ Dvec,
    const int* __restrict__ length,
    float* __restrict__ y)
{
  extern __shared__ char smem[];
  float* sBr = (float*)(smem + O_BR);
  float* sBi = (float*)(smem + O_BI);
  float* sK  = (float*)(smem + O_K);

  const int tid = threadIdx.x;
  const int l = tid & 63;
  const int wv = tid >> 6;
  const int h = blockIdx.x & 255;
  const int b = blockIdx.x >> 8;
  const size_t base = ((size_t)b * H_SZ + h) * L_SZ;
  const float* up = u + base;

  // ---- per-lane mode params (r6/r7 verbatim) ----
  const float dt = expf(log_dt[h]);
  const float ar = expf(log_A_real[h * 64 + l]);
  const float ai = A_imag[h * 64 + l];
  const float er = expf(-ar * dt);
  const float th = ai * dt;
  const float wr = er * cosf(th), wi = er * sinf(th);
  const float em1r = wr - 1.0f, em1i = wi;
  const float inv = 1.0f / (ar * ar + ai * ai);
  const float qr = (em1i * ai - em1r * ar) * inv;
  const float qi = -(em1r * ai + em1i * ar) * inv;
  const float c0 = Cin[(h * 64 + l) * 2 + 0];
  const float c1 = Cin[(h * 64 + l) * 2 + 1];
  const float c2r = 2.0f * (c0 * qr - c1 * qi);
  const float c2i = 2.0f * (c0 * qi + c1 * qr);

  const float w2r = wr*wr - wi*wi,     w2i = 2.f*wr*wi;
  const float w4r = w2r*w2r - w2i*w2i, w4i = 2.f*w2r*w2i;
  const float w8r = w4r*w4r - w4i*w4i, w8i = 2.f*w4r*w4i;
  const float w16r= w8r*w8r - w8i*w8i, w16i= 2.f*w8r*w8i;

  float b0r = 1.f, b0i = 0.f;                 // w^{16*wv}
  for (int s2 = 0; s2 < wv; ++s2) {
    const float nr = b0r*w16r - b0i*w16i, ni = b0r*w16i + b0i*w16r;
    b0r = nr; b0i = ni;
  }

  // ---- phase A: stage U (fp32 -> fp16, XOR-swizzled) [r7 verbatim] ----
  {
    const int e0 = tid * 16;
    const float4 f0 = *(const float4*)(up + e0);
    const float4 f1 = *(const float4*)(up + e0 + 4);
    const float4 f2 = *(const float4*)(up + e0 + 8);
    const float4 f3 = *(const float4*)(up + e0 + 12);
    s16x8 v0, v1;
    v0[0]=(short)f2h(f0.x); v0[1]=(short)f2h(f0.y);
    v0[2]=(short)f2h(f0.z); v0[3]=(short)f2h(f0.w);
    v0[4]=(short)f2h(f1.x); v0[5]=(short)f2h(f1.y);
    v0[6]=(short)f2h(f1.z); v0[7]=(short)f2h(f1.w);
    v1[0]=(short)f2h(f2.x); v1[1]=(short)f2h(f2.y);
    v1[2]=(short)f2h(f2.z); v1[3]=(short)f2h(f2.w);
    v1[4]=(short)f2h(f3.x); v1[5]=(short)f2h(f3.y);
    v1[6]=(short)f2h(f3.z); v1[7]=(short)f2h(f3.w);
    const int r = tid >> 2;
    const int q0 = (2 * tid) & 7;
    char* ub = smem + O_U + r * 128;
    *(s16x8*)(ub + (((q0    ) ^ (r & 7)) << 4)) = v0;
    *(s16x8*)(ub + (((q0 + 1) ^ (r & 7)) << 4)) = v1;
  }

  // ---- phase V: V[n=l][63-k] = w^k (fp16 swz) [r7 verbatim] ----
  {
    float pr = b0r, pi = b0i;
    #pragma unroll
    for (int kk = 0; kk < 16; ++kk) {
      const int k = wv * 16 + kk;
      const int c63 = 63 - k;
      const int vb = l * 128 + (((c63 >> 3) ^ (l & 7)) << 4) + (c63 & 7) * 2;
      *(unsigned short*)(smem + O_VR + vb) = f2h(pr);
      *(unsigned short*)(smem + O_VI + vb) = f2h(pi);
      const float nr = pr*wr - pi*wi, ni = pr*wi + pi*wr;
      pr = nr; pi = ni;
    }
  }

  // ---- phase G/K: K[k] -> sK (fp32, proven); G rows fp16 swz (GRAFT) ----
  {
    float pr = b0r, pi = b0i;                // w^k
    #pragma unroll
    for (int kk = 0; kk < 16; ++kk) {
      const int k = 16*wv + kk;
      const float gre = c2r*pr - c2i*pi;     // Re(2Ct w^k)
      const float gim = c2r*pi + c2i*pr;
      float s = gre;
      #pragma unroll
      for (int m = 1; m < 64; m <<= 1) s += __shfl_xor(s, m, 64);
      if (l == 0) sK[k] = s;
      if (k >= 1) {                          // G[k-1][n=l] = 2Ct w^k
        const int row = k - 1;
        const int gb = row * 128 + (((l >> 3) ^ (row & 7)) << 4) + (l & 7) * 2;
        *(unsigned short*)(smem + O_GR + gb) = f2h(gre);
        *(unsigned short*)(smem + O_GM + gb) = f2h(-gim);
      }
      const float nr = pr*wr - pi*wi, ni = pr*wi + pi*wr;
      pr = nr; pi = ni;
    }
    if (wv == 3) {                           // row 63: 2Ct w^64
      const float gre = c2r*pr - c2i*pi;
      const float gim = c2r*pi + c2i*pr;
      const int gb = 63 * 128 + (((l >> 3) ^ 7) << 4) + (l & 7) * 2;
      *(unsigned short*)(smem + O_GR + gb) = f2h(gre);
      *(unsigned short*)(smem + O_GM + gb) = f2h(-gim);
    }
  }
  __syncthreads();

  // ---- phase C: Tt[tau][s] = K[tau-s] (fp16 swz) from sK (GRAFT) ----
  {
    const int tau = tid >> 2;
    const int sb = tid & 3;
    #pragma unroll
    for (int half = 0; half < 2; ++half) {
      const int q = sb * 2 + half;
      s16x8 v;
      #pragma unroll
      for (int e = 0; e < 8; ++e) {
        const int s = q * 8 + e;
        float kv = 0.0f;
        if (s <= tau) kv = sK[tau - s];
        v[e] = (short)f2h(kv);
      }
      *(s16x8*)(smem + O_TT + tau * 128 + ((q ^ (tau & 7)) << 4)) = v;
    }
  }
  __syncthreads();

  auto frag = [&](int base_, int row, int kc) -> s16x8 {
    return *(const s16x8*)(smem + base_ + row * 128 + ((kc ^ (row & 7)) << 4));
  };
  const int arow = 16 * wv + (l & 15);
  const int kq = l >> 4;
  const s16x8 aU0 = frag(O_U, arow, kq);
  const s16x8 aU1 = frag(O_U, arow, 4 + kq);

  // ---- B-GEMM: B = U.V^T via MFMA, B written fp32 [r7 verbatim] ----
  {
    f32x4 accR[4], accI[4];
    #pragma unroll
    for (int j = 0; j < 4; ++j) { accR[j] = f32x4{0,0,0,0}; accI[j] = f32x4{0,0,0,0}; }
    #pragma unroll
    for (int j = 0; j < 4; ++j) {
      const int bcol = 16 * j + (l & 15);
      accR[j] = MFMA(aU0, frag(O_VR, bcol, kq),     accR[j]);
      accR[j] = MFMA(aU1, frag(O_VR, bcol, 4 + kq), accR[j]);
      accI[j] = MFMA(aU0, frag(O_VI, bcol, kq),     accI[j]);
      accI[j] = MFMA(aU1, frag(O_VI, bcol, 4 + kq), accI[j]);
    }
    #pragma unroll
    for (int j = 0; j < 4; ++j) {
      const int n = 16 * j + (l & 15);
      #pragma unroll
      for (int r = 0; r < 4; ++r) {
        const int c = 16 * wv + (l >> 4) * 4 + r;
        sBr[c * 64 + n] = accR[j][r];        // clobbers sK (dead)
        sBi[c * 64 + n] = accI[j][r];
      }
    }
  }
  __syncthreads();   // VR/VI dead; scan may overwrite them with X

  // ---- scan (wave 0): fp32 states, X[c]=pre-state stored fp16 swz (GRAFT) ----
  if (wv == 0) {
    const float l2r = w16r*w16r - w16i*w16i, l2i = 2.f*w16r*w16i; // w^32
    const float lr  = l2r*l2r - l2i*l2i,     li  = 2.f*l2r*l2i;   // w^64
    float xr = 0.f, xi = 0.f;
    for (int c = 0; c < 64; ++c) {
      const int xo = c * 128 + (((l >> 3) ^ (c & 7)) << 4) + (l & 7) * 2;
      *(unsigned short*)(smem + O_XR + xo) = f2h(xr);
      *(unsigned short*)(smem + O_XI + xo) = f2h(xi);
      const float br = sBr[c*64 + l];
      const float bi = sBi[c*64 + l];
      const float nr = fmaf(lr, xr, fmaf(-li, xi, br));
      const float ni = fmaf(lr, xi, fmaf(li, xr, bi));
      xr = nr; xi = ni;
    }
  }
  __syncthreads();

  // ---- phase 3: Y = U.Tt^T + Xr.Gr^T + Xi.Gm^T via MFMA (GRAFT) ----
  f32x4 acc[4];
  #pragma unroll
  for (int j = 0; j < 4; ++j) acc[j] = f32x4{0,0,0,0};
  const s16x8 aXr0 = frag(O_XR, arow, kq);
  const s16x8 aXr1 = frag(O_XR, arow, 4 + kq);
  const s16x8 aXi0 = frag(O_XI, arow, kq);
  const s16x8 aXi1 = frag(O_XI, arow, 4 + kq);
  #pragma unroll
  for (int j = 0; j < 4; ++j) {
    const int bcol = 16 * j + (l & 15);
    acc[j] = MFMA(aU0,  frag(O_TT, bcol, kq),     acc[j]);
    acc[j] = MFMA(aU1,  frag(O_TT, bcol, 4 + kq), acc[j]);
    acc[j] = MFMA(aXr0, frag(O_GR, bcol, kq),     acc[j]);
    acc[j] = MFMA(aXr1, frag(O_GR, bcol, 4 + kq), acc[j]);
    acc[j] = MFMA(aXi0, frag(O_GM, bcol, kq),     acc[j]);
    acc[j] = MFMA(aXi1, frag(O_GM, bcol, 4 + kq), acc[j]);
  }

  // ---- epilogue: y = acc + D*u, length mask [r5 mapping == r7-proven] ----
  const float Dh = Dvec[h];
  const int len = length[b];
  float* yp = y + base;
  #pragma unroll
  for (int j = 0; j < 4; ++j) {
    #pragma unroll
    for (int r = 0; r < 4; ++r) {
      const int t = (16 * wv + (l >> 4) * 4 + r) * 64 + 16 * j + (l & 15);
      const float out = fmaf(Dh, up[t], acc[j][r]);
      yp[t] = (t < len) ? out : 0.0f;
    }
  }
}

extern "C" void kernel_launch(void* const* d_in, const int* in_sizes, int n_in,
                              void* d_out, int out_size, void* d_ws, size_t ws_size,
                              hipStream_t stream) {
  const float* u          = (const float*)d_in[0];
  const float* log_dt     = (const float*)d_in[1];
  const float* C          = (const float*)d_in[2];
  const float* log_A_real = (const float*)d_in[3];
  const float* A_imag     = (const float*)d_in[4];
  const float* D          = (const float*)d_in[5];
  const int*   length     = (const int*)d_in[6];
  float* y = (float*)d_out;

  dssm_mfma<<<B_SZ * H_SZ, 256, LDS_TOTAL, stream>>>(
      u, log_dt, C, log_A_real, A_imag, D, length, y);
}

// Round 14
// 92.277 us; speedup vs baseline: 7.4308x; 1.1635x over previous
//
#include <hip/hip_runtime.h>

// DSS forward, chunked-parallel scan, all GEMMs on MFMA (fp16 ops, fp32 accum).
// r14 = r12(=r8)-proven kernel + ONLY the two bit-neutral micro-opts from r13:
//  - Phase-3 dual accumulators (accT: U.Tt; accX: X.G) -> 8 independent MFMA
//    chains; summed in epilogue. Register-only.
//  - Scan unrolled x4 (batches independent B reads ahead of the FMA chain).
// r13's opt-1 (D folded into Tt, fp16 D*u) REMOVED: it passed the first absmax
// check (0.0625 @ line 488) but failed the post-timing re-validation (line 515)
// -> D*u must stay on the exact fp32 path. Epilogue = r8 verbatim.

#define B_SZ 16
#define H_SZ 256
#define L_SZ 4096

using s16x8 = __attribute__((ext_vector_type(8))) short;
using h16x8 = __attribute__((ext_vector_type(8))) _Float16;
using f32x4 = __attribute__((ext_vector_type(4))) float;

template <typename T>
__device__ inline auto mfma_try(T a, T b, f32x4 c, int)
    -> decltype(__builtin_amdgcn_mfma_f32_16x16x32_f16(a, b, c, 0, 0, 0)) {
  return __builtin_amdgcn_mfma_f32_16x16x32_f16(a, b, c, 0, 0, 0);
}
template <typename T>
__device__ inline f32x4 mfma_try(T a, T b, f32x4 c, long) {
  return __builtin_amdgcn_mfma_f32_16x16x32_f16(
      __builtin_bit_cast(h16x8, a), __builtin_bit_cast(h16x8, b), c, 0, 0, 0);
}
__device__ inline f32x4 MFMA(s16x8 a, s16x8 b, f32x4 c) {
  return mfma_try(a, b, c, 0);
}

__device__ inline unsigned short f2h(float f) {
  return __builtin_bit_cast(unsigned short, (_Float16)f);   // RNE
}

// ---- LDS map (80 KB exactly -> 2 blocks/CU; identical to r8) ----
#define O_U   0          // fp16 [64][64] swz; alive through phase 3
#define O_VR  8192       // fp16 [64][64] swz; dead after B-GEMM -> X real
#define O_VI  16384      // fp16 [64][64] swz; dead after B-GEMM -> X imag
#define O_XR  O_VR
#define O_XI  O_VI
#define O_TT  24576      // fp16 [64][64] swz: Tt[tau][s] = K[tau-s]
#define O_GR  32768      // fp16 [64][64] swz: G[tau][n] =  Re(2Ct w^{tau+1})
#define O_GM  40960      // fp16 [64][64] swz:            = -Im(2Ct w^{tau+1})
#define O_BR  49152      // f32 [64][64] B real (scan source)
#define O_BI  65536      // f32 [64][64] B imag
#define O_K   O_BR       // f32[64] K; dead before B-GEMM clobbers O_BR
#define LDS_TOTAL 81920

__global__ __launch_bounds__(256) void dssm_mfma(
    const float* __restrict__ u,
    const float* __restrict__ log_dt,
    const float* __restrict__ Cin,
    const float* __restrict__ log_A_real,
    const float* __restrict__ A_imag,
    const float* __restrict__ Dvec,
    const int* __restrict__ length,
    float* __restrict__ y)
{
  extern __shared__ char smem[];
  float* sBr = (float*)(smem + O_BR);
  float* sBi = (float*)(smem + O_BI);
  float* sK  = (float*)(smem + O_K);

  const int tid = threadIdx.x;
  const int l = tid & 63;
  const int wv = tid >> 6;
  const int h = blockIdx.x & 255;
  const int b = blockIdx.x >> 8;
  const size_t base = ((size_t)b * H_SZ + h) * L_SZ;
  const float* up = u + base;

  // ---- per-lane mode params (r8 verbatim) ----
  const float dt = expf(log_dt[h]);
  const float ar = expf(log_A_real[h * 64 + l]);
  const float ai = A_imag[h * 64 + l];
  const float er = expf(-ar * dt);
  const float th = ai * dt;
  const float wr = er * cosf(th), wi = er * sinf(th);
  const float em1r = wr - 1.0f, em1i = wi;
  const float inv = 1.0f / (ar * ar + ai * ai);
  const float qr = (em1i * ai - em1r * ar) * inv;
  const float qi = -(em1r * ai + em1i * ar) * inv;
  const float c0 = Cin[(h * 64 + l) * 2 + 0];
  const float c1 = Cin[(h * 64 + l) * 2 + 1];
  const float c2r = 2.0f * (c0 * qr - c1 * qi);
  const float c2i = 2.0f * (c0 * qi + c1 * qr);

  const float w2r = wr*wr - wi*wi,     w2i = 2.f*wr*wi;
  const float w4r = w2r*w2r - w2i*w2i, w4i = 2.f*w2r*w2i;
  const float w8r = w4r*w4r - w4i*w4i, w8i = 2.f*w4r*w4i;
  const float w16r= w8r*w8r - w8i*w8i, w16i= 2.f*w8r*w8i;

  float b0r = 1.f, b0i = 0.f;                 // w^{16*wv}
  for (int s2 = 0; s2 < wv; ++s2) {
    const float nr = b0r*w16r - b0i*w16i, ni = b0r*w16i + b0i*w16r;
    b0r = nr; b0i = ni;
  }

  // ---- phase A: stage U (fp32 -> fp16, XOR-swizzled) [r8 verbatim] ----
  {
    const int e0 = tid * 16;
    const float4 f0 = *(const float4*)(up + e0);
    const float4 f1 = *(const float4*)(up + e0 + 4);
    const float4 f2 = *(const float4*)(up + e0 + 8);
    const float4 f3 = *(const float4*)(up + e0 + 12);
    s16x8 v0, v1;
    v0[0]=(short)f2h(f0.x); v0[1]=(short)f2h(f0.y);
    v0[2]=(short)f2h(f0.z); v0[3]=(short)f2h(f0.w);
    v0[4]=(short)f2h(f1.x); v0[5]=(short)f2h(f1.y);
    v0[6]=(short)f2h(f1.z); v0[7]=(short)f2h(f1.w);
    v1[0]=(short)f2h(f2.x); v1[1]=(short)f2h(f2.y);
    v1[2]=(short)f2h(f2.z); v1[3]=(short)f2h(f2.w);
    v1[4]=(short)f2h(f3.x); v1[5]=(short)f2h(f3.y);
    v1[6]=(short)f2h(f3.z); v1[7]=(short)f2h(f3.w);
    const int r = tid >> 2;
    const int q0 = (2 * tid) & 7;
    char* ub = smem + O_U + r * 128;
    *(s16x8*)(ub + (((q0    ) ^ (r & 7)) << 4)) = v0;
    *(s16x8*)(ub + (((q0 + 1) ^ (r & 7)) << 4)) = v1;
  }

  // ---- phase V: V[n=l][63-k] = w^k (fp16 swz) [r8 verbatim] ----
  {
    float pr = b0r, pi = b0i;
    #pragma unroll
    for (int kk = 0; kk < 16; ++kk) {
      const int k = wv * 16 + kk;
      const int c63 = 63 - k;
      const int vb = l * 128 + (((c63 >> 3) ^ (l & 7)) << 4) + (c63 & 7) * 2;
      *(unsigned short*)(smem + O_VR + vb) = f2h(pr);
      *(unsigned short*)(smem + O_VI + vb) = f2h(pi);
      const float nr = pr*wr - pi*wi, ni = pr*wi + pi*wr;
      pr = nr; pi = ni;
    }
  }

  // ---- phase G/K: K[k] -> sK (fp32); G rows fp16 swz [r8 verbatim] ----
  {
    float pr = b0r, pi = b0i;                // w^k
    #pragma unroll
    for (int kk = 0; kk < 16; ++kk) {
      const int k = 16*wv + kk;
      const float gre = c2r*pr - c2i*pi;     // Re(2Ct w^k)
      const float gim = c2r*pi + c2i*pr;
      float s = gre;
      #pragma unroll
      for (int m = 1; m < 64; m <<= 1) s += __shfl_xor(s, m, 64);
      if (l == 0) sK[k] = s;
      if (k >= 1) {                          // G[k-1][n=l] = 2Ct w^k
        const int row = k - 1;
        const int gb = row * 128 + (((l >> 3) ^ (row & 7)) << 4) + (l & 7) * 2;
        *(unsigned short*)(smem + O_GR + gb) = f2h(gre);
        *(unsigned short*)(smem + O_GM + gb) = f2h(-gim);
      }
      const float nr = pr*wr - pi*wi, ni = pr*wi + pi*wr;
      pr = nr; pi = ni;
    }
    if (wv == 3) {                           // row 63: 2Ct w^64
      const float gre = c2r*pr - c2i*pi;
      const float gim = c2r*pi + c2i*pr;
      const int gb = 63 * 128 + (((l >> 3) ^ 7) << 4) + (l & 7) * 2;
      *(unsigned short*)(smem + O_GR + gb) = f2h(gre);
      *(unsigned short*)(smem + O_GM + gb) = f2h(-gim);
    }
  }
  __syncthreads();

  // ---- phase C: Tt[tau][s] = K[tau-s] (fp16 swz) [r8 verbatim, NO D-fold] ----
  {
    const int tau = tid >> 2;
    const int sb = tid & 3;
    #pragma unroll
    for (int half = 0; half < 2; ++half) {
      const int q = sb * 2 + half;
      s16x8 v;
      #pragma unroll
      for (int e = 0; e < 8; ++e) {
        const int s = q * 8 + e;
        float kv = 0.0f;
        if (s <= tau) kv = sK[tau - s];
        v[e] = (short)f2h(kv);
      }
      *(s16x8*)(smem + O_TT + tau * 128 + ((q ^ (tau & 7)) << 4)) = v;
    }
  }
  __syncthreads();

  auto frag = [&](int base_, int row, int kc) -> s16x8 {
    return *(const s16x8*)(smem + base_ + row * 128 + ((kc ^ (row & 7)) << 4));
  };
  const int arow = 16 * wv + (l & 15);
  const int kq = l >> 4;
  const s16x8 aU0 = frag(O_U, arow, kq);
  const s16x8 aU1 = frag(O_U, arow, 4 + kq);

  // ---- B-GEMM: B = U.V^T via MFMA, B written fp32 [r8 verbatim] ----
  {
    f32x4 accR[4], accI[4];
    #pragma unroll
    for (int j = 0; j < 4; ++j) { accR[j] = f32x4{0,0,0,0}; accI[j] = f32x4{0,0,0,0}; }
    #pragma unroll
    for (int j = 0; j < 4; ++j) {
      const int bcol = 16 * j + (l & 15);
      accR[j] = MFMA(aU0, frag(O_VR, bcol, kq),     accR[j]);
      accR[j] = MFMA(aU1, frag(O_VR, bcol, 4 + kq), accR[j]);
      accI[j] = MFMA(aU0, frag(O_VI, bcol, kq),     accI[j]);
      accI[j] = MFMA(aU1, frag(O_VI, bcol, 4 + kq), accI[j]);
    }
    #pragma unroll
    for (int j = 0; j < 4; ++j) {
      const int n = 16 * j + (l & 15);
      #pragma unroll
      for (int r = 0; r < 4; ++r) {
        const int c = 16 * wv + (l >> 4) * 4 + r;
        sBr[c * 64 + n] = accR[j][r];        // clobbers sK (dead)
        sBi[c * 64 + n] = accI[j][r];
      }
    }
  }
  __syncthreads();   // VR/VI dead; scan overwrites them with X

  // ---- scan (wave 0): fp32 states, X fp16 swz [r8 + unroll 4] ----
  if (wv == 0) {
    const float l2r = w16r*w16r - w16i*w16i, l2i = 2.f*w16r*w16i; // w^32
    const float lr  = l2r*l2r - l2i*l2i,     li  = 2.f*l2r*l2i;   // w^64
    float xr = 0.f, xi = 0.f;
    #pragma unroll 4
    for (int c = 0; c < 64; ++c) {
      const int xo = c * 128 + (((l >> 3) ^ (c & 7)) << 4) + (l & 7) * 2;
      *(unsigned short*)(smem + O_XR + xo) = f2h(xr);
      *(unsigned short*)(smem + O_XI + xo) = f2h(xi);
      const float br = sBr[c*64 + l];
      const float bi = sBi[c*64 + l];
      const float nr = fmaf(lr, xr, fmaf(-li, xi, br));
      const float ni = fmaf(lr, xi, fmaf(li, xr, bi));
      xr = nr; xi = ni;
    }
  }
  __syncthreads();

  // ---- phase 3: Y via MFMA, dual accumulator chains ----
  f32x4 accT[4], accX[4];
  #pragma unroll
  for (int j = 0; j < 4; ++j) { accT[j] = f32x4{0,0,0,0}; accX[j] = f32x4{0,0,0,0}; }
  const s16x8 aXr0 = frag(O_XR, arow, kq);
  const s16x8 aXr1 = frag(O_XR, arow, 4 + kq);
  const s16x8 aXi0 = frag(O_XI, arow, kq);
  const s16x8 aXi1 = frag(O_XI, arow, 4 + kq);
  #pragma unroll
  for (int j = 0; j < 4; ++j) {
    const int bcol = 16 * j + (l & 15);
    accT[j] = MFMA(aU0,  frag(O_TT, bcol, kq),     accT[j]);
    accT[j] = MFMA(aU1,  frag(O_TT, bcol, 4 + kq), accT[j]);
    accX[j] = MFMA(aXr0, frag(O_GR, bcol, kq),     accX[j]);
    accX[j] = MFMA(aXr1, frag(O_GR, bcol, 4 + kq), accX[j]);
    accX[j] = MFMA(aXi0, frag(O_GM, bcol, kq),     accX[j]);
    accX[j] = MFMA(aXi1, frag(O_GM, bcol, 4 + kq), accX[j]);
  }

  // ---- epilogue: y = accT + accX + D*u (fp32 global u), length mask [r8] ----
  const float Dh = Dvec[h];
  const int len = length[b];
  float* yp = y + base;
  #pragma unroll
  for (int j = 0; j < 4; ++j) {
    #pragma unroll
    for (int r = 0; r < 4; ++r) {
      const int t = (16 * wv + (l >> 4) * 4 + r) * 64 + 16 * j + (l & 15);
      const float out = fmaf(Dh, up[t], accT[j][r] + accX[j][r]);
      yp[t] = (t < len) ? out : 0.0f;
    }
  }
}

extern "C" void kernel_launch(void* const* d_in, const int* in_sizes, int n_in,
                              void* d_out, int out_size, void* d_ws, size_t ws_size,
                              hipStream_t stream) {
  const float* u          = (const float*)d_in[0];
  const float* log_dt     = (const float*)d_in[1];
  const float* C          = (const float*)d_in[2];
  const float* log_A_real = (const float*)d_in[3];
  const float* A_imag     = (const float*)d_in[4];
  const float* D          = (const float*)d_in[5];
  const int*   length     = (const int*)d_in[6];
  float* y = (float*)d_out;

  dssm_mfma<<<B_SZ * H_SZ, 256, LDS_TOTAL, stream>>>(
      u, log_dt, C, log_A_real, A_imag, D, length, y);
}

// Round 15
// 63.409 us; speedup vs baseline: 10.8137x; 1.4553x over previous
//
#include <hip/hip_runtime.h>

// DSS forward, chunked-parallel scan, all GEMMs on MFMA (fp16 ops, fp32 accum).
// r15: two-kernel design. Per-head prep (V/G/K/Tt/lambda) hoisted into a setup
// kernel (256 blocks, one per head) writing LINEAR fp16 mats + fp32 lam to ws;
// main kernel (r14-proven GEMM/scan/epilogue) stages mats with the r7-PROVEN
// store-side-swizzle pattern (no global_load_lds), barriers 5 -> 3, no
// transcendentals. 16 same-head blocks share each head's 40KB via L2/L3.
// Historical note: r3/r4/r5's failures all traced to LDS-B fp16 packing (absent
// here); the ws mechanism itself showed structured (intact-mats) errors.
// Fallback: if ws_size < 10.6MB, launch the r14 single-kernel path (determin.).

#define B_SZ 16
#define H_SZ 256
#define L_SZ 4096

using s16x8 = __attribute__((ext_vector_type(8))) short;
using h16x8 = __attribute__((ext_vector_type(8))) _Float16;
using f32x4 = __attribute__((ext_vector_type(4))) float;

template <typename T>
__device__ inline auto mfma_try(T a, T b, f32x4 c, int)
    -> decltype(__builtin_amdgcn_mfma_f32_16x16x32_f16(a, b, c, 0, 0, 0)) {
  return __builtin_amdgcn_mfma_f32_16x16x32_f16(a, b, c, 0, 0, 0);
}
template <typename T>
__device__ inline f32x4 mfma_try(T a, T b, f32x4 c, long) {
  return __builtin_amdgcn_mfma_f32_16x16x32_f16(
      __builtin_bit_cast(h16x8, a), __builtin_bit_cast(h16x8, b), c, 0, 0, 0);
}
__device__ inline f32x4 MFMA(s16x8 a, s16x8 b, f32x4 c) {
  return mfma_try(a, b, c, 0);
}

__device__ inline unsigned short f2h(float f) {
  return __builtin_bit_cast(unsigned short, (_Float16)f);   // RNE
}

// ---- LDS map (80 KB exactly -> 2 blocks/CU; identical to r14) ----
#define O_U   0          // fp16 [64][64] swz
#define O_VR  8192       // fp16 [64][64] swz; dead after B-GEMM -> X real
#define O_VI  16384      // fp16 [64][64] swz; dead after B-GEMM -> X imag
#define O_XR  O_VR
#define O_XI  O_VI
#define O_TT  24576      // fp16 [64][64] swz
#define O_GR  32768      // fp16 [64][64] swz
#define O_GM  40960      // fp16 [64][64] swz
#define O_BR  49152      // f32 [64][64] B real (scan source)
#define O_BI  65536      // f32 [64][64] B imag
#define O_K   O_BR       // (fallback kernel only)
#define LDS_TOTAL 81920

#define MATS_SHORTS_PER_H (5 * 4096)
#define WS_MATS_BYTES ((size_t)H_SZ * MATS_SHORTS_PER_H * 2)       // 10.0 MB
#define WS_LAM_OFF    WS_MATS_BYTES
#define WS_NEEDED     (WS_MATS_BYTES + (size_t)H_SZ * 64 * 2 * 4)  // +128 KB

// ====================== setup: per-head mats (r14 prep, linear out) ======
__global__ __launch_bounds__(256) void dssm_setup(
    const float* __restrict__ log_dt,
    const float* __restrict__ Cin,
    const float* __restrict__ log_A_real,
    const float* __restrict__ A_imag,
    unsigned short* __restrict__ mats,   // per h: {Vr,Vi,Tt,Gr,Gm} 5x64x64
    float* __restrict__ lam)             // per h: 64 x (re,im) of w^64
{
  __shared__ unsigned short sm[5 * 4096];
  __shared__ float sKs[64];
  const int tid = threadIdx.x;
  const int l = tid & 63;
  const int wv = tid >> 6;
  const int h = blockIdx.x;

  // ---- per-lane mode params (r14 verbatim) ----
  const float dt = expf(log_dt[h]);
  const float ar = expf(log_A_real[h * 64 + l]);
  const float ai = A_imag[h * 64 + l];
  const float er = expf(-ar * dt);
  const float th = ai * dt;
  const float wr = er * cosf(th), wi = er * sinf(th);
  const float em1r = wr - 1.0f, em1i = wi;
  const float inv = 1.0f / (ar * ar + ai * ai);
  const float qr = (em1i * ai - em1r * ar) * inv;
  const float qi = -(em1r * ai + em1i * ar) * inv;
  const float c0 = Cin[(h * 64 + l) * 2 + 0];
  const float c1 = Cin[(h * 64 + l) * 2 + 1];
  const float c2r = 2.0f * (c0 * qr - c1 * qi);
  const float c2i = 2.0f * (c0 * qi + c1 * qr);

  const float w2r = wr*wr - wi*wi,     w2i = 2.f*wr*wi;
  const float w4r = w2r*w2r - w2i*w2i, w4i = 2.f*w2r*w2i;
  const float w8r = w4r*w4r - w4i*w4i, w8i = 2.f*w4r*w4i;
  const float w16r= w8r*w8r - w8i*w8i, w16i= 2.f*w8r*w8i;

  float b0r = 1.f, b0i = 0.f;                 // w^{16*wv}
  for (int s2 = 0; s2 < wv; ++s2) {
    const float nr = b0r*w16r - b0i*w16i, ni = b0r*w16i + b0i*w16r;
    b0r = nr; b0i = ni;
  }

  // ---- V: V[n=l][63-k] = w^k (LINEAR) ----
  {
    float pr = b0r, pi = b0i;
    #pragma unroll
    for (int kk = 0; kk < 16; ++kk) {
      const int k = wv * 16 + kk;
      sm[0 * 4096 + l * 64 + (63 - k)] = f2h(pr);
      sm[1 * 4096 + l * 64 + (63 - k)] = f2h(pi);
      const float nr = pr*wr - pi*wi, ni = pr*wi + pi*wr;
      pr = nr; pi = ni;
    }
  }

  // ---- G/K: K[k] -> sKs; G rows LINEAR; lam = w^64 (wv==3 tail) ----
  {
    float pr = b0r, pi = b0i;                // w^k
    #pragma unroll
    for (int kk = 0; kk < 16; ++kk) {
      const int k = 16*wv + kk;
      const float gre = c2r*pr - c2i*pi;     // Re(2Ct w^k)
      const float gim = c2r*pi + c2i*pr;
      float s = gre;
      #pragma unroll
      for (int m = 1; m < 64; m <<= 1) s += __shfl_xor(s, m, 64);
      if (l == 0) sKs[k] = s;
      if (k >= 1) {                          // G[k-1][n=l]
        sm[3 * 4096 + (k - 1) * 64 + l] = f2h(gre);
        sm[4 * 4096 + (k - 1) * 64 + l] = f2h(-gim);
      }
      const float nr = pr*wr - pi*wi, ni = pr*wi + pi*wr;
      pr = nr; pi = ni;
    }
    if (wv == 3) {                           // k=64: G row 63 + lam
      const float gre = c2r*pr - c2i*pi;
      const float gim = c2r*pi + c2i*pr;
      sm[3 * 4096 + 63 * 64 + l] = f2h(gre);
      sm[4 * 4096 + 63 * 64 + l] = f2h(-gim);
      lam[(h * 64 + l) * 2 + 0] = pr;        // w^64
      lam[(h * 64 + l) * 2 + 1] = pi;
    }
  }
  __syncthreads();

  // ---- Tt[tau][s] = K[tau-s] (LINEAR); thread -> (tau = tid>>2, 16 cols) ----
  {
    const int tau = tid >> 2;
    const int sb = (tid & 3) * 16;
    #pragma unroll
    for (int e = 0; e < 16; ++e) {
      const int s = sb + e;
      const float kv = (s <= tau) ? sKs[tau - s] : 0.0f;
      sm[2 * 4096 + tau * 64 + s] = f2h(kv);
    }
  }
  __syncthreads();

  // ---- coalesced copy-out: 20480 shorts = 2560 chunks, 10 per thread ----
  unsigned short* dst = mats + (size_t)h * MATS_SHORTS_PER_H;
  #pragma unroll
  for (int i = 0; i < 10; ++i) {
    const int c = i * 256 + tid;
    *(s16x8*)(dst + c * 8) = *(const s16x8*)(sm + c * 8);
  }
}

// ====================== main: r14 GEMM/scan/epilogue, mats from ws ======
__global__ __launch_bounds__(256) void dssm_main(
    const float* __restrict__ u,
    const unsigned short* __restrict__ mats,
    const float* __restrict__ lam,
    const float* __restrict__ Dvec,
    const int* __restrict__ length,
    float* __restrict__ y)
{
  extern __shared__ char smem[];
  float* sBr = (float*)(smem + O_BR);
  float* sBi = (float*)(smem + O_BI);

  const int tid = threadIdx.x;
  const int l = tid & 63;
  const int wv = tid >> 6;
  const int h = blockIdx.x & 255;
  const int b = blockIdx.x >> 8;
  const size_t base = ((size_t)b * H_SZ + h) * L_SZ;
  const float* up = u + base;

  // early scalar/vector loads (latency hidden under staging)
  const float Dh = Dvec[h];
  const int len = length[b];
  const float lr = lam[(h * 64 + l) * 2 + 0];   // w^64 (scan, wave 0)
  const float li = lam[(h * 64 + l) * 2 + 1];

  // ---- phase A: stage U (fp32 -> fp16, XOR-swizzled) [r14 verbatim] ----
  {
    const int e0 = tid * 16;
    const float4 f0 = *(const float4*)(up + e0);
    const float4 f1 = *(const float4*)(up + e0 + 4);
    const float4 f2 = *(const float4*)(up + e0 + 8);
    const float4 f3 = *(const float4*)(up + e0 + 12);
    s16x8 v0, v1;
    v0[0]=(short)f2h(f0.x); v0[1]=(short)f2h(f0.y);
    v0[2]=(short)f2h(f0.z); v0[3]=(short)f2h(f0.w);
    v0[4]=(short)f2h(f1.x); v0[5]=(short)f2h(f1.y);
    v0[6]=(short)f2h(f1.z); v0[7]=(short)f2h(f1.w);
    v1[0]=(short)f2h(f2.x); v1[1]=(short)f2h(f2.y);
    v1[2]=(short)f2h(f2.z); v1[3]=(short)f2h(f2.w);
    v1[4]=(short)f2h(f3.x); v1[5]=(short)f2h(f3.y);
    v1[6]=(short)f2h(f3.z); v1[7]=(short)f2h(f3.w);
    const int r = tid >> 2;
    const int q0 = (2 * tid) & 7;
    char* ub = smem + O_U + r * 128;
    *(s16x8*)(ub + (((q0    ) ^ (r & 7)) << 4)) = v0;
    *(s16x8*)(ub + (((q0 + 1) ^ (r & 7)) << 4)) = v1;
  }

  // ---- phase M: stage 5 mats, store-side swizzle (r7-proven pattern) ----
  {
    const unsigned short* mb = mats + (size_t)h * MATS_SHORTS_PER_H;
    const int r = tid >> 2;                 // logical row (same math as phase A)
    const int q0 = (2 * tid) & 7;           // 16B-chunk column
    const int rsw = r & 7;
    #pragma unroll
    for (int m = 0; m < 5; ++m) {
      const s16x8 va = *(const s16x8*)(mb + m * 4096 + tid * 16);
      const s16x8 vb = *(const s16x8*)(mb + m * 4096 + tid * 16 + 8);
      char* bs = smem + 8192 + m * 8192 + r * 128;   // VR,VI,TT,GR,GM
      *(s16x8*)(bs + (((q0    ) ^ rsw) << 4)) = va;
      *(s16x8*)(bs + (((q0 + 1) ^ rsw) << 4)) = vb;
    }
  }
  __syncthreads();                          // sync1: U + all mats visible

  auto frag = [&](int base_, int row, int kc) -> s16x8 {
    return *(const s16x8*)(smem + base_ + row * 128 + ((kc ^ (row & 7)) << 4));
  };
  const int arow = 16 * wv + (l & 15);
  const int kq = l >> 4;
  const s16x8 aU0 = frag(O_U, arow, kq);
  const s16x8 aU1 = frag(O_U, arow, 4 + kq);

  // ---- B-GEMM: B = U.V^T via MFMA, B written fp32 [r14 verbatim] ----
  {
    f32x4 accR[4], accI[4];
    #pragma unroll
    for (int j = 0; j < 4; ++j) { accR[j] = f32x4{0,0,0,0}; accI[j] = f32x4{0,0,0,0}; }
    #pragma unroll
    for (int j = 0; j < 4; ++j) {
      const int bcol = 16 * j + (l & 15);
      accR[j] = MFMA(aU0, frag(O_VR, bcol, kq),     accR[j]);
      accR[j] = MFMA(aU1, frag(O_VR, bcol, 4 + kq), accR[j]);
      accI[j] = MFMA(aU0, frag(O_VI, bcol, kq),     accI[j]);
      accI[j] = MFMA(aU1, frag(O_VI, bcol, 4 + kq), accI[j]);
    }
    #pragma unroll
    for (int j = 0; j < 4; ++j) {
      const int n = 16 * j + (l & 15);
      #pragma unroll
      for (int r = 0; r < 4; ++r) {
        const int c = 16 * wv + (l >> 4) * 4 + r;
        sBr[c * 64 + n] = accR[j][r];
        sBi[c * 64 + n] = accI[j][r];
      }
    }
  }
  __syncthreads();                          // sync2: B complete; V dead

  // ---- scan (wave 0): fp32 states, X fp16 swz [r14 verbatim, lam from ws] ----
  if (wv == 0) {
    float xr = 0.f, xi = 0.f;
    #pragma unroll 4
    for (int c = 0; c < 64; ++c) {
      const int xo = c * 128 + (((l >> 3) ^ (c & 7)) << 4) + (l & 7) * 2;
      *(unsigned short*)(smem + O_XR + xo) = f2h(xr);
      *(unsigned short*)(smem + O_XI + xo) = f2h(xi);
      const float br = sBr[c*64 + l];
      const float bi = sBi[c*64 + l];
      const float nr = fmaf(lr, xr, fmaf(-li, xi, br));
      const float ni = fmaf(lr, xi, fmaf(li, xr, bi));
      xr = nr; xi = ni;
    }
  }
  __syncthreads();                          // sync3: X visible

  // ---- phase 3: Y via MFMA, dual accumulator chains [r14 verbatim] ----
  f32x4 accT[4], accX[4];
  #pragma unroll
  for (int j = 0; j < 4; ++j) { accT[j] = f32x4{0,0,0,0}; accX[j] = f32x4{0,0,0,0}; }
  const s16x8 aXr0 = frag(O_XR, arow, kq);
  const s16x8 aXr1 = frag(O_XR, arow, 4 + kq);
  const s16x8 aXi0 = frag(O_XI, arow, kq);
  const s16x8 aXi1 = frag(O_XI, arow, 4 + kq);
  #pragma unroll
  for (int j = 0; j < 4; ++j) {
    const int bcol = 16 * j + (l & 15);
    accT[j] = MFMA(aU0,  frag(O_TT, bcol, kq),     accT[j]);
    accT[j] = MFMA(aU1,  frag(O_TT, bcol, 4 + kq), accT[j]);
    accX[j] = MFMA(aXr0, frag(O_GR, bcol, kq),     accX[j]);
    accX[j] = MFMA(aXr1, frag(O_GR, bcol, 4 + kq), accX[j]);
    accX[j] = MFMA(aXi0, frag(O_GM, bcol, kq),     accX[j]);
    accX[j] = MFMA(aXi1, frag(O_GM, bcol, 4 + kq), accX[j]);
  }

  // ---- epilogue: y = accT + accX + D*u (fp32 global u) [r14 verbatim] ----
  float* yp = y + base;
  #pragma unroll
  for (int j = 0; j < 4; ++j) {
    #pragma unroll
    for (int r = 0; r < 4; ++r) {
      const int t = (16 * wv + (l >> 4) * 4 + r) * 64 + 16 * j + (l & 15);
      const float out = fmaf(Dh, up[t], accT[j][r] + accX[j][r]);
      yp[t] = (t < len) ? out : 0.0f;
    }
  }
}

// ====================== fallback: r14 single kernel (ws too small) ======
__global__ __launch_bounds__(256) void dssm_fb(
    const float* __restrict__ u,
    const float* __restrict__ log_dt,
    const float* __restrict__ Cin,
    const float* __restrict__ log_A_real,
    const float* __restrict__ A_imag,
    const float* __restrict__ Dvec,
    const int* __restrict__ length,
    float* __restrict__ y)
{
  extern __shared__ char smem[];
  float* sBr = (float*)(smem + O_BR);
  float* sBi = (float*)(smem + O_BI);
  float* sK  = (float*)(smem + O_K);

  const int tid = threadIdx.x;
  const int l = tid & 63;
  const int wv = tid >> 6;
  const int h = blockIdx.x & 255;
  const int b = blockIdx.x >> 8;
  const size_t base = ((size_t)b * H_SZ + h) * L_SZ;
  const float* up = u + base;

  const float dt = expf(log_dt[h]);
  const float ar = expf(log_A_real[h * 64 + l]);
  const float ai = A_imag[h * 64 + l];
  const float er = expf(-ar * dt);
  const float th = ai * dt;
  const float wr = er * cosf(th), wi = er * sinf(th);
  const float em1r = wr - 1.0f, em1i = wi;
  const float inv = 1.0f / (ar * ar + ai * ai);
  const float qr = (em1i * ai - em1r * ar) * inv;
  const float qi = -(em1r * ai + em1i * ar) * inv;
  const float c0 = Cin[(h * 64 + l) * 2 + 0];
  const float c1 = Cin[(h * 64 + l) * 2 + 1];
  const float c2r = 2.0f * (c0 * qr - c1 * qi);
  const float c2i = 2.0f * (c0 * qi + c1 * qr);

  const float w2r = wr*wr - wi*wi,     w2i = 2.f*wr*wi;
  const float w4r = w2r*w2r - w2i*w2i, w4i = 2.f*w2r*w2i;
  const float w8r = w4r*w4r - w4i*w4i, w8i = 2.f*w4r*w4i;
  const float w16r= w8r*w8r - w8i*w8i, w16i= 2.f*w8r*w8i;

  float b0r = 1.f, b0i = 0.f;
  for (int s2 = 0; s2 < wv; ++s2) {
    const float nr = b0r*w16r - b0i*w16i, ni = b0r*w16i + b0i*w16r;
    b0r = nr; b0i = ni;
  }

  {
    const int e0 = tid * 16;
    const float4 f0 = *(const float4*)(up + e0);
    const float4 f1 = *(const float4*)(up + e0 + 4);
    const float4 f2 = *(const float4*)(up + e0 + 8);
    const float4 f3 = *(const float4*)(up + e0 + 12);
    s16x8 v0, v1;
    v0[0]=(short)f2h(f0.x); v0[1]=(short)f2h(f0.y);
    v0[2]=(short)f2h(f0.z); v0[3]=(short)f2h(f0.w);
    v0[4]=(short)f2h(f1.x); v0[5]=(short)f2h(f1.y);
    v0[6]=(short)f2h(f1.z); v0[7]=(short)f2h(f1.w);
    v1[0]=(short)f2h(f2.x); v1[1]=(short)f2h(f2.y);
    v1[2]=(short)f2h(f2.z); v1[3]=(short)f2h(f2.w);
    v1[4]=(short)f2h(f3.x); v1[5]=(short)f2h(f3.y);
    v1[6]=(short)f2h(f3.z); v1[7]=(short)f2h(f3.w);
    const int r = tid >> 2;
    const int q0 = (2 * tid) & 7;
    char* ub = smem + O_U + r * 128;
    *(s16x8*)(ub + (((q0    ) ^ (r & 7)) << 4)) = v0;
    *(s16x8*)(ub + (((q0 + 1) ^ (r & 7)) << 4)) = v1;
  }
  {
    float pr = b0r, pi = b0i;
    #pragma unroll
    for (int kk = 0; kk < 16; ++kk) {
      const int k = wv * 16 + kk;
      const int c63 = 63 - k;
      const int vb = l * 128 + (((c63 >> 3) ^ (l & 7)) << 4) + (c63 & 7) * 2;
      *(unsigned short*)(smem + O_VR + vb) = f2h(pr);
      *(unsigned short*)(smem + O_VI + vb) = f2h(pi);
      const float nr = pr*wr - pi*wi, ni = pr*wi + pi*wr;
      pr = nr; pi = ni;
    }
  }
  {
    float pr = b0r, pi = b0i;
    #pragma unroll
    for (int kk = 0; kk < 16; ++kk) {
      const int k = 16*wv + kk;
      const float gre = c2r*pr - c2i*pi;
      const float gim = c2r*pi + c2i*pr;
      float s = gre;
      #pragma unroll
      for (int m = 1; m < 64; m <<= 1) s += __shfl_xor(s, m, 64);
      if (l == 0) sK[k] = s;
      if (k >= 1) {
        const int row = k - 1;
        const int gb = row * 128 + (((l >> 3) ^ (row & 7)) << 4) + (l & 7) * 2;
        *(unsigned short*)(smem + O_GR + gb) = f2h(gre);
        *(unsigned short*)(smem + O_GM + gb) = f2h(-gim);
      }
      const float nr = pr*wr - pi*wi, ni = pr*wi + pi*wr;
      pr = nr; pi = ni;
    }
    if (wv == 3) {
      const float gre = c2r*pr - c2i*pi;
      const float gim = c2r*pi + c2i*pr;
      const int gb = 63 * 128 + (((l >> 3) ^ 7) << 4) + (l & 7) * 2;
      *(unsigned short*)(smem + O_GR + gb) = f2h(gre);
      *(unsigned short*)(smem + O_GM + gb) = f2h(-gim);
    }
  }
  __syncthreads();
  {
    const int tau = tid >> 2;
    const int sb = tid & 3;
    #pragma unroll
    for (int half = 0; half < 2; ++half) {
      const int q = sb * 2 + half;
      s16x8 v;
      #pragma unroll
      for (int e = 0; e < 8; ++e) {
        const int s = q * 8 + e;
        float kv = 0.0f;
        if (s <= tau) kv = sK[tau - s];
        v[e] = (short)f2h(kv);
      }
      *(s16x8*)(smem + O_TT + tau * 128 + ((q ^ (tau & 7)) << 4)) = v;
    }
  }
  __syncthreads();

  auto frag = [&](int base_, int row, int kc) -> s16x8 {
    return *(const s16x8*)(smem + base_ + row * 128 + ((kc ^ (row & 7)) << 4));
  };
  const int arow = 16 * wv + (l & 15);
  const int kq = l >> 4;
  const s16x8 aU0 = frag(O_U, arow, kq);
  const s16x8 aU1 = frag(O_U, arow, 4 + kq);

  {
    f32x4 accR[4], accI[4];
    #pragma unroll
    for (int j = 0; j < 4; ++j) { accR[j] = f32x4{0,0,0,0}; accI[j] = f32x4{0,0,0,0}; }
    #pragma unroll
    for (int j = 0; j < 4; ++j) {
      const int bcol = 16 * j + (l & 15);
      accR[j] = MFMA(aU0, frag(O_VR, bcol, kq),     accR[j]);
      accR[j] = MFMA(aU1, frag(O_VR, bcol, 4 + kq), accR[j]);
      accI[j] = MFMA(aU0, frag(O_VI, bcol, kq),     accI[j]);
      accI[j] = MFMA(aU1, frag(O_VI, bcol, 4 + kq), accI[j]);
    }
    #pragma unroll
    for (int j = 0; j < 4; ++j) {
      const int n = 16 * j + (l & 15);
      #pragma unroll
      for (int r = 0; r < 4; ++r) {
        const int c = 16 * wv + (l >> 4) * 4 + r;
        sBr[c * 64 + n] = accR[j][r];
        sBi[c * 64 + n] = accI[j][r];
      }
    }
  }
  __syncthreads();

  if (wv == 0) {
    const float l2r = w16r*w16r - w16i*w16i, l2i = 2.f*w16r*w16i;
    const float lr  = l2r*l2r - l2i*l2i,     li  = 2.f*l2r*l2i;
    float xr = 0.f, xi = 0.f;
    #pragma unroll 4
    for (int c = 0; c < 64; ++c) {
      const int xo = c * 128 + (((l >> 3) ^ (c & 7)) << 4) + (l & 7) * 2;
      *(unsigned short*)(smem + O_XR + xo) = f2h(xr);
      *(unsigned short*)(smem + O_XI + xo) = f2h(xi);
      const float br = sBr[c*64 + l];
      const float bi = sBi[c*64 + l];
      const float nr = fmaf(lr, xr, fmaf(-li, xi, br));
      const float ni = fmaf(lr, xi, fmaf(li, xr, bi));
      xr = nr; xi = ni;
    }
  }
  __syncthreads();

  f32x4 accT[4], accX[4];
  #pragma unroll
  for (int j = 0; j < 4; ++j) { accT[j] = f32x4{0,0,0,0}; accX[j] = f32x4{0,0,0,0}; }
  const s16x8 aXr0 = frag(O_XR, arow, kq);
  const s16x8 aXr1 = frag(O_XR, arow, 4 + kq);
  const s16x8 aXi0 = frag(O_XI, arow, kq);
  const s16x8 aXi1 = frag(O_XI, arow, 4 + kq);
  #pragma unroll
  for (int j = 0; j < 4; ++j) {
    const int bcol = 16 * j + (l & 15);
    accT[j] = MFMA(aU0,  frag(O_TT, bcol, kq),     accT[j]);
    accT[j] = MFMA(aU1,  frag(O_TT, bcol, 4 + kq), accT[j]);
    accX[j] = MFMA(aXr0, frag(O_GR, bcol, kq),     accX[j]);
    accX[j] = MFMA(aXr1, frag(O_GR, bcol, 4 + kq), accX[j]);
    accX[j] = MFMA(aXi0, frag(O_GM, bcol, kq),     accX[j]);
    accX[j] = MFMA(aXi1, frag(O_GM, bcol, 4 + kq), accX[j]);
  }

  const float Dh = Dvec[h];
  const int len = length[b];
  float* yp = y + base;
  #pragma unroll
  for (int j = 0; j < 4; ++j) {
    #pragma unroll
    for (int r = 0; r < 4; ++r) {
      const int t = (16 * wv + (l >> 4) * 4 + r) * 64 + 16 * j + (l & 15);
      const float out = fmaf(Dh, up[t], accT[j][r] + accX[j][r]);
      yp[t] = (t < len) ? out : 0.0f;
    }
  }
}

extern "C" void kernel_launch(void* const* d_in, const int* in_sizes, int n_in,
                              void* d_out, int out_size, void* d_ws, size_t ws_size,
                              hipStream_t stream) {
  const float* u          = (const float*)d_in[0];
  const float* log_dt     = (const float*)d_in[1];
  const float* C          = (const float*)d_in[2];
  const float* log_A_real = (const float*)d_in[3];
  const float* A_imag     = (const float*)d_in[4];
  const float* D          = (const float*)d_in[5];
  const int*   length     = (const int*)d_in[6];
  float* y = (float*)d_out;

  if (ws_size >= WS_NEEDED && d_ws != nullptr) {
    unsigned short* mats = (unsigned short*)d_ws;
    float* lam = (float*)((char*)d_ws + WS_LAM_OFF);
    dssm_setup<<<H_SZ, 256, 0, stream>>>(log_dt, C, log_A_real, A_imag,
                                         mats, lam);
    dssm_main<<<B_SZ * H_SZ, 256, LDS_TOTAL, stream>>>(u, mats, lam, D,
                                                       length, y);
  } else {
    dssm_fb<<<B_SZ * H_SZ, 256, LDS_TOTAL, stream>>>(
        u, log_dt, C, log_A_real, A_imag, D, length, y);
  }
}

// Round 16
// 63.165 us; speedup vs baseline: 10.8555x; 1.0039x over previous
//
#include <hip/hip_runtime.h>

// DSS forward, chunked-parallel scan, all GEMMs on MFMA (fp16 ops, fp32 accum).
// r16 = r15 two-kernel design + three audited latency cuts:
//  1. Setup writes mats PRE-SWIZZLED to ws; main stages them with linear
//     global_load_lds (rule #21: producer-side swizzle + linear DMA; bytes
//     identical to r15's store-side-swizzled LDS by construction).
//  2. accT (U.Tt, independent of X) runs in the scan slot for waves 1-3
//     (wave 0 runs it after sync3) -> serial scan hidden under MFMA work.
//     accT reads O_TT only; scan touches B/X regions -> disjoint, race-free.
//  3. Epilogue u prefetched into ureg[16] (static) before the accX cluster.
// Barrier structure, wave assignment, LDS map, math order: unchanged vs r15.

#define B_SZ 16
#define H_SZ 256
#define L_SZ 4096

using s16x8 = __attribute__((ext_vector_type(8))) short;
using h16x8 = __attribute__((ext_vector_type(8))) _Float16;
using f32x4 = __attribute__((ext_vector_type(4))) float;

template <typename T>
__device__ inline auto mfma_try(T a, T b, f32x4 c, int)
    -> decltype(__builtin_amdgcn_mfma_f32_16x16x32_f16(a, b, c, 0, 0, 0)) {
  return __builtin_amdgcn_mfma_f32_16x16x32_f16(a, b, c, 0, 0, 0);
}
template <typename T>
__device__ inline f32x4 mfma_try(T a, T b, f32x4 c, long) {
  return __builtin_amdgcn_mfma_f32_16x16x32_f16(
      __builtin_bit_cast(h16x8, a), __builtin_bit_cast(h16x8, b), c, 0, 0, 0);
}
__device__ inline f32x4 MFMA(s16x8 a, s16x8 b, f32x4 c) {
  return mfma_try(a, b, c, 0);
}

__device__ inline unsigned short f2h(float f) {
  return __builtin_bit_cast(unsigned short, (_Float16)f);   // RNE
}

// ---- LDS map (80 KB exactly -> 2 blocks/CU; identical to r15) ----
#define O_U   0          // fp16 [64][64] swz
#define O_VR  8192       // fp16 [64][64] swz; dead after B-GEMM -> X real
#define O_VI  16384      // fp16 [64][64] swz; dead after B-GEMM -> X imag
#define O_XR  O_VR
#define O_XI  O_VI
#define O_TT  24576      // fp16 [64][64] swz
#define O_GR  32768      // fp16 [64][64] swz
#define O_GM  40960      // fp16 [64][64] swz
#define O_BR  49152      // f32 [64][64] B real (scan source)
#define O_BI  65536      // f32 [64][64] B imag
#define O_K   O_BR       // (fallback kernel only)
#define LDS_TOTAL 81920

#define MATS_SHORTS_PER_H (5 * 4096)
#define WS_MATS_BYTES ((size_t)H_SZ * MATS_SHORTS_PER_H * 2)       // 10.0 MB
#define WS_LAM_OFF    WS_MATS_BYTES
#define WS_NEEDED     (WS_MATS_BYTES + (size_t)H_SZ * 64 * 2 * 4)  // +128 KB

// ====================== setup: per-head mats, PRE-SWIZZLED ======
__global__ __launch_bounds__(256) void dssm_setup(
    const float* __restrict__ log_dt,
    const float* __restrict__ Cin,
    const float* __restrict__ log_A_real,
    const float* __restrict__ A_imag,
    unsigned short* __restrict__ mats,   // per h: {Vr,Vi,Tt,Gr,Gm}, swizzled
    float* __restrict__ lam)             // per h: 64 x (re,im) of w^64
{
  __shared__ unsigned short sm[5 * 4096];
  __shared__ float sKs[64];
  const int tid = threadIdx.x;
  const int l = tid & 63;
  const int wv = tid >> 6;
  const int h = blockIdx.x;
  char* smb = (char*)sm;

  // ---- per-lane mode params (r15 verbatim) ----
  const float dt = expf(log_dt[h]);
  const float ar = expf(log_A_real[h * 64 + l]);
  const float ai = A_imag[h * 64 + l];
  const float er = expf(-ar * dt);
  const float th = ai * dt;
  const float wr = er * cosf(th), wi = er * sinf(th);
  const float em1r = wr - 1.0f, em1i = wi;
  const float inv = 1.0f / (ar * ar + ai * ai);
  const float qr = (em1i * ai - em1r * ar) * inv;
  const float qi = -(em1r * ai + em1i * ar) * inv;
  const float c0 = Cin[(h * 64 + l) * 2 + 0];
  const float c1 = Cin[(h * 64 + l) * 2 + 1];
  const float c2r = 2.0f * (c0 * qr - c1 * qi);
  const float c2i = 2.0f * (c0 * qi + c1 * qr);

  const float w2r = wr*wr - wi*wi,     w2i = 2.f*wr*wi;
  const float w4r = w2r*w2r - w2i*w2i, w4i = 2.f*w2r*w2i;
  const float w8r = w4r*w4r - w4i*w4i, w8i = 2.f*w4r*w4i;
  const float w16r= w8r*w8r - w8i*w8i, w16i= 2.f*w8r*w8i;

  float b0r = 1.f, b0i = 0.f;                 // w^{16*wv}
  for (int s2 = 0; s2 < wv; ++s2) {
    const float nr = b0r*w16r - b0i*w16i, ni = b0r*w16i + b0i*w16r;
    b0r = nr; b0i = ni;
  }

  // ---- V: V[n=l][63-k] = w^k, SWIZZLED (r14-fb-proven offsets) ----
  {
    float pr = b0r, pi = b0i;
    #pragma unroll
    for (int kk = 0; kk < 16; ++kk) {
      const int k = wv * 16 + kk;
      const int c63 = 63 - k;
      const int vb = l * 128 + (((c63 >> 3) ^ (l & 7)) << 4) + (c63 & 7) * 2;
      *(unsigned short*)(smb + 0 * 8192 + vb) = f2h(pr);
      *(unsigned short*)(smb + 1 * 8192 + vb) = f2h(pi);
      const float nr = pr*wr - pi*wi, ni = pr*wi + pi*wr;
      pr = nr; pi = ni;
    }
  }

  // ---- G/K: K[k] -> sKs; G rows SWIZZLED; lam = w^64 (wv==3 tail) ----
  {
    float pr = b0r, pi = b0i;                // w^k
    #pragma unroll
    for (int kk = 0; kk < 16; ++kk) {
      const int k = 16*wv + kk;
      const float gre = c2r*pr - c2i*pi;     // Re(2Ct w^k)
      const float gim = c2r*pi + c2i*pr;
      float s = gre;
      #pragma unroll
      for (int m = 1; m < 64; m <<= 1) s += __shfl_xor(s, m, 64);
      if (l == 0) sKs[k] = s;
      if (k >= 1) {                          // G[k-1][n=l]
        const int row = k - 1;
        const int gb = row * 128 + (((l >> 3) ^ (row & 7)) << 4) + (l & 7) * 2;
        *(unsigned short*)(smb + 3 * 8192 + gb) = f2h(gre);
        *(unsigned short*)(smb + 4 * 8192 + gb) = f2h(-gim);
      }
      const float nr = pr*wr - pi*wi, ni = pr*wi + pi*wr;
      pr = nr; pi = ni;
    }
    if (wv == 3) {                           // k=64: G row 63 + lam
      const float gre = c2r*pr - c2i*pi;
      const float gim = c2r*pi + c2i*pr;
      const int gb = 63 * 128 + (((l >> 3) ^ 7) << 4) + (l & 7) * 2;
      *(unsigned short*)(smb + 3 * 8192 + gb) = f2h(gre);
      *(unsigned short*)(smb + 4 * 8192 + gb) = f2h(-gim);
      lam[(h * 64 + l) * 2 + 0] = pr;        // w^64
      lam[(h * 64 + l) * 2 + 1] = pi;
    }
  }
  __syncthreads();

  // ---- Tt[tau][s] = K[tau-s], SWIZZLED (r14-fb-proven offsets) ----
  {
    const int tau = tid >> 2;
    const int sb = tid & 3;
    #pragma unroll
    for (int half = 0; half < 2; ++half) {
      const int q = sb * 2 + half;
      s16x8 v;
      #pragma unroll
      for (int e = 0; e < 8; ++e) {
        const int s = q * 8 + e;
        const float kv = (s <= tau) ? sKs[tau - s] : 0.0f;
        v[e] = (short)f2h(kv);
      }
      *(s16x8*)(smb + 2 * 8192 + tau * 128 + ((q ^ (tau & 7)) << 4)) = v;
    }
  }
  __syncthreads();

  // ---- coalesced copy-out: 2560 chunks of 16 B, 10 per thread ----
  unsigned short* dst = mats + (size_t)h * MATS_SHORTS_PER_H;
  #pragma unroll
  for (int i = 0; i < 10; ++i) {
    const int c = i * 256 + tid;
    *(s16x8*)(dst + c * 8) = *(const s16x8*)(sm + c * 8);
  }
}

// ====================== main: GEMM/scan/epilogue, mats via gload_lds ======
__global__ __launch_bounds__(256) void dssm_main(
    const float* __restrict__ u,
    const unsigned short* __restrict__ mats,
    const float* __restrict__ lam,
    const float* __restrict__ Dvec,
    const int* __restrict__ length,
    float* __restrict__ y)
{
  extern __shared__ char smem[];
  float* sBr = (float*)(smem + O_BR);
  float* sBi = (float*)(smem + O_BI);

  const int tid = threadIdx.x;
  const int l = tid & 63;
  const int wv = tid >> 6;
  const int h = blockIdx.x & 255;
  const int b = blockIdx.x >> 8;
  const size_t base = ((size_t)b * H_SZ + h) * L_SZ;
  const float* up = u + base;

  // early scalar/vector loads
  const float Dh = Dvec[h];
  const int len = length[b];
  const float lr = lam[(h * 64 + l) * 2 + 0];   // w^64 (scan, wave 0)
  const float li = lam[(h * 64 + l) * 2 + 1];

  // ---- phase M: fire-and-forget mats DMA (linear; pre-swizzled in ws) ----
  {
    const unsigned short* mb = mats + (size_t)h * MATS_SHORTS_PER_H;
    for (int g = wv; g < 40; g += 4) {         // 10 issues/wave, 1 KB each
      const unsigned short* src = mb + g * 512 + l * 8;
      __builtin_amdgcn_global_load_lds(
          (const __attribute__((address_space(1))) void*)src,
          (__attribute__((address_space(3))) void*)(smem + 8192 + g * 1024),
          16, 0, 0);
    }
  }

  // ---- phase A: stage U (fp32 -> fp16, XOR-swizzled) [r15 verbatim] ----
  {
    const int e0 = tid * 16;
    const float4 f0 = *(const float4*)(up + e0);
    const float4 f1 = *(const float4*)(up + e0 + 4);
    const float4 f2 = *(const float4*)(up + e0 + 8);
    const float4 f3 = *(const float4*)(up + e0 + 12);
    s16x8 v0, v1;
    v0[0]=(short)f2h(f0.x); v0[1]=(short)f2h(f0.y);
    v0[2]=(short)f2h(f0.z); v0[3]=(short)f2h(f0.w);
    v0[4]=(short)f2h(f1.x); v0[5]=(short)f2h(f1.y);
    v0[6]=(short)f2h(f1.z); v0[7]=(short)f2h(f1.w);
    v1[0]=(short)f2h(f2.x); v1[1]=(short)f2h(f2.y);
    v1[2]=(short)f2h(f2.z); v1[3]=(short)f2h(f2.w);
    v1[4]=(short)f2h(f3.x); v1[5]=(short)f2h(f3.y);
    v1[6]=(short)f2h(f3.z); v1[7]=(short)f2h(f3.w);
    const int r = tid >> 2;
    const int q0 = (2 * tid) & 7;
    char* ub = smem + O_U + r * 128;
    *(s16x8*)(ub + (((q0    ) ^ (r & 7)) << 4)) = v0;
    *(s16x8*)(ub + (((q0 + 1) ^ (r & 7)) << 4)) = v1;
  }
  __syncthreads();                          // sync1: U + all mats visible

  auto frag = [&](int base_, int row, int kc) -> s16x8 {
    return *(const s16x8*)(smem + base_ + row * 128 + ((kc ^ (row & 7)) << 4));
  };
  const int arow = 16 * wv + (l & 15);
  const int kq = l >> 4;
  const s16x8 aU0 = frag(O_U, arow, kq);
  const s16x8 aU1 = frag(O_U, arow, 4 + kq);

  // ---- B-GEMM: B = U.V^T via MFMA, B written fp32 [r15 verbatim] ----
  {
    f32x4 accR[4], accI[4];
    #pragma unroll
    for (int j = 0; j < 4; ++j) { accR[j] = f32x4{0,0,0,0}; accI[j] = f32x4{0,0,0,0}; }
    #pragma unroll
    for (int j = 0; j < 4; ++j) {
      const int bcol = 16 * j + (l & 15);
      accR[j] = MFMA(aU0, frag(O_VR, bcol, kq),     accR[j]);
      accR[j] = MFMA(aU1, frag(O_VR, bcol, 4 + kq), accR[j]);
      accI[j] = MFMA(aU0, frag(O_VI, bcol, kq),     accI[j]);
      accI[j] = MFMA(aU1, frag(O_VI, bcol, 4 + kq), accI[j]);
    }
    #pragma unroll
    for (int j = 0; j < 4; ++j) {
      const int n = 16 * j + (l & 15);
      #pragma unroll
      for (int r = 0; r < 4; ++r) {
        const int c = 16 * wv + (l >> 4) * 4 + r;
        sBr[c * 64 + n] = accR[j][r];
        sBi[c * 64 + n] = accI[j][r];
      }
    }
  }
  __syncthreads();                          // sync2: B complete; V dead

  // ---- scan slot: wave 0 scans; waves 1-3 run accT (U.Tt, X-independent) ----
  f32x4 accT[4];
  #pragma unroll
  for (int j = 0; j < 4; ++j) accT[j] = f32x4{0,0,0,0};
  auto do_accT = [&]() {
    #pragma unroll
    for (int j = 0; j < 4; ++j) {
      const int bcol = 16 * j + (l & 15);
      accT[j] = MFMA(aU0, frag(O_TT, bcol, kq),     accT[j]);
      accT[j] = MFMA(aU1, frag(O_TT, bcol, 4 + kq), accT[j]);
    }
  };
  if (wv == 0) {
    // fp32 serial scan, X fp16 swz into dead V region [r15 verbatim]
    float xr = 0.f, xi = 0.f;
    #pragma unroll 4
    for (int c = 0; c < 64; ++c) {
      const int xo = c * 128 + (((l >> 3) ^ (c & 7)) << 4) + (l & 7) * 2;
      *(unsigned short*)(smem + O_XR + xo) = f2h(xr);
      *(unsigned short*)(smem + O_XI + xo) = f2h(xi);
      const float br = sBr[c*64 + l];
      const float bi = sBi[c*64 + l];
      const float nr = fmaf(lr, xr, fmaf(-li, xi, br));
      const float ni = fmaf(lr, xi, fmaf(li, xr, bi));
      xr = nr; xi = ni;
    }
  } else {
    do_accT();                              // reads O_TT only: disjoint
  }
  __syncthreads();                          // sync3: X visible

  // ---- epilogue u prefetch (issue-early, consume-late) ----
  float ureg[16];
  #pragma unroll
  for (int j = 0; j < 4; ++j) {
    #pragma unroll
    for (int r = 0; r < 4; ++r) {
      ureg[j * 4 + r] = up[(16 * wv + (l >> 4) * 4 + r) * 64 + 16 * j + (l & 15)];
    }
  }

  if (wv == 0) do_accT();                   // wave 0's accT (TT still stable)

  // ---- accX: X.G via MFMA [r15 verbatim] ----
  f32x4 accX[4];
  #pragma unroll
  for (int j = 0; j < 4; ++j) accX[j] = f32x4{0,0,0,0};
  const s16x8 aXr0 = frag(O_XR, arow, kq);
  const s16x8 aXr1 = frag(O_XR, arow, 4 + kq);
  const s16x8 aXi0 = frag(O_XI, arow, kq);
  const s16x8 aXi1 = frag(O_XI, arow, 4 + kq);
  #pragma unroll
  for (int j = 0; j < 4; ++j) {
    const int bcol = 16 * j + (l & 15);
    accX[j] = MFMA(aXr0, frag(O_GR, bcol, kq),     accX[j]);
    accX[j] = MFMA(aXr1, frag(O_GR, bcol, 4 + kq), accX[j]);
    accX[j] = MFMA(aXi0, frag(O_GM, bcol, kq),     accX[j]);
    accX[j] = MFMA(aXi1, frag(O_GM, bcol, 4 + kq), accX[j]);
  }

  // ---- epilogue: y = accT + accX + D*u (fp32), length mask ----
  float* yp = y + base;
  #pragma unroll
  for (int j = 0; j < 4; ++j) {
    #pragma unroll
    for (int r = 0; r < 4; ++r) {
      const int t = (16 * wv + (l >> 4) * 4 + r) * 64 + 16 * j + (l & 15);
      const float out = fmaf(Dh, ureg[j * 4 + r], accT[j][r] + accX[j][r]);
      yp[t] = (t < len) ? out : 0.0f;
    }
  }
}

// ====================== fallback: r14 single kernel (ws too small) ======
__global__ __launch_bounds__(256) void dssm_fb(
    const float* __restrict__ u,
    const float* __restrict__ log_dt,
    const float* __restrict__ Cin,
    const float* __restrict__ log_A_real,
    const float* __restrict__ A_imag,
    const float* __restrict__ Dvec,
    const int* __restrict__ length,
    float* __restrict__ y)
{
  extern __shared__ char smem[];
  float* sBr = (float*)(smem + O_BR);
  float* sBi = (float*)(smem + O_BI);
  float* sK  = (float*)(smem + O_K);

  const int tid = threadIdx.x;
  const int l = tid & 63;
  const int wv = tid >> 6;
  const int h = blockIdx.x & 255;
  const int b = blockIdx.x >> 8;
  const size_t base = ((size_t)b * H_SZ + h) * L_SZ;
  const float* up = u + base;

  const float dt = expf(log_dt[h]);
  const float ar = expf(log_A_real[h * 64 + l]);
  const float ai = A_imag[h * 64 + l];
  const float er = expf(-ar * dt);
  const float th = ai * dt;
  const float wr = er * cosf(th), wi = er * sinf(th);
  const float em1r = wr - 1.0f, em1i = wi;
  const float inv = 1.0f / (ar * ar + ai * ai);
  const float qr = (em1i * ai - em1r * ar) * inv;
  const float qi = -(em1r * ai + em1i * ar) * inv;
  const float c0 = Cin[(h * 64 + l) * 2 + 0];
  const float c1 = Cin[(h * 64 + l) * 2 + 1];
  const float c2r = 2.0f * (c0 * qr - c1 * qi);
  const float c2i = 2.0f * (c0 * qi + c1 * qr);

  const float w2r = wr*wr - wi*wi,     w2i = 2.f*wr*wi;
  const float w4r = w2r*w2r - w2i*w2i, w4i = 2.f*w2r*w2i;
  const float w8r = w4r*w4r - w4i*w4i, w8i = 2.f*w4r*w4i;
  const float w16r= w8r*w8r - w8i*w8i, w16i= 2.f*w8r*w8i;

  float b0r = 1.f, b0i = 0.f;
  for (int s2 = 0; s2 < wv; ++s2) {
    const float nr = b0r*w16r - b0i*w16i, ni = b0r*w16i + b0i*w16r;
    b0r = nr; b0i = ni;
  }

  {
    const int e0 = tid * 16;
    const float4 f0 = *(const float4*)(up + e0);
    const float4 f1 = *(const float4*)(up + e0 + 4);
    const float4 f2 = *(const float4*)(up + e0 + 8);
    const float4 f3 = *(const float4*)(up + e0 + 12);
    s16x8 v0, v1;
    v0[0]=(short)f2h(f0.x); v0[1]=(short)f2h(f0.y);
    v0[2]=(short)f2h(f0.z); v0[3]=(short)f2h(f0.w);
    v0[4]=(short)f2h(f1.x); v0[5]=(short)f2h(f1.y);
    v0[6]=(short)f2h(f1.z); v0[7]=(short)f2h(f1.w);
    v1[0]=(short)f2h(f2.x); v1[1]=(short)f2h(f2.y);
    v1[2]=(short)f2h(f2.z); v1[3]=(short)f2h(f2.w);
    v1[4]=(short)f2h(f3.x); v1[5]=(short)f2h(f3.y);
    v1[6]=(short)f2h(f3.z); v1[7]=(short)f2h(f3.w);
    const int r = tid >> 2;
    const int q0 = (2 * tid) & 7;
    char* ub = smem + O_U + r * 128;
    *(s16x8*)(ub + (((q0    ) ^ (r & 7)) << 4)) = v0;
    *(s16x8*)(ub + (((q0 + 1) ^ (r & 7)) << 4)) = v1;
  }
  {
    float pr = b0r, pi = b0i;
    #pragma unroll
    for (int kk = 0; kk < 16; ++kk) {
      const int k = wv * 16 + kk;
      const int c63 = 63 - k;
      const int vb = l * 128 + (((c63 >> 3) ^ (l & 7)) << 4) + (c63 & 7) * 2;
      *(unsigned short*)(smem + O_VR + vb) = f2h(pr);
      *(unsigned short*)(smem + O_VI + vb) = f2h(pi);
      const float nr = pr*wr - pi*wi, ni = pr*wi + pi*wr;
      pr = nr; pi = ni;
    }
  }
  {
    float pr = b0r, pi = b0i;
    #pragma unroll
    for (int kk = 0; kk < 16; ++kk) {
      const int k = 16*wv + kk;
      const float gre = c2r*pr - c2i*pi;
      const float gim = c2r*pi + c2i*pr;
      float s = gre;
      #pragma unroll
      for (int m = 1; m < 64; m <<= 1) s += __shfl_xor(s, m, 64);
      if (l == 0) sK[k] = s;
      if (k >= 1) {
        const int row = k - 1;
        const int gb = row * 128 + (((l >> 3) ^ (row & 7)) << 4) + (l & 7) * 2;
        *(unsigned short*)(smem + O_GR + gb) = f2h(gre);
        *(unsigned short*)(smem + O_GM + gb) = f2h(-gim);
      }
      const float nr = pr*wr - pi*wi, ni = pr*wi + pi*wr;
      pr = nr; pi = ni;
    }
    if (wv == 3) {
      const float gre = c2r*pr - c2i*pi;
      const float gim = c2r*pi + c2i*pr;
      const int gb = 63 * 128 + (((l >> 3) ^ 7) << 4) + (l & 7) * 2;
      *(unsigned short*)(smem + O_GR + gb) = f2h(gre);
      *(unsigned short*)(smem + O_GM + gb) = f2h(-gim);
    }
  }
  __syncthreads();
  {
    const int tau = tid >> 2;
    const int sb = tid & 3;
    #pragma unroll
    for (int half = 0; half < 2; ++half) {
      const int q = sb * 2 + half;
      s16x8 v;
      #pragma unroll
      for (int e = 0; e < 8; ++e) {
        const int s = q * 8 + e;
        float kv = 0.0f;
        if (s <= tau) kv = sK[tau - s];
        v[e] = (short)f2h(kv);
      }
      *(s16x8*)(smem + O_TT + tau * 128 + ((q ^ (tau & 7)) << 4)) = v;
    }
  }
  __syncthreads();

  auto frag = [&](int base_, int row, int kc) -> s16x8 {
    return *(const s16x8*)(smem + base_ + row * 128 + ((kc ^ (row & 7)) << 4));
  };
  const int arow = 16 * wv + (l & 15);
  const int kq = l >> 4;
  const s16x8 aU0 = frag(O_U, arow, kq);
  const s16x8 aU1 = frag(O_U, arow, 4 + kq);

  {
    f32x4 accR[4], accI[4];
    #pragma unroll
    for (int j = 0; j < 4; ++j) { accR[j] = f32x4{0,0,0,0}; accI[j] = f32x4{0,0,0,0}; }
    #pragma unroll
    for (int j = 0; j < 4; ++j) {
      const int bcol = 16 * j + (l & 15);
      accR[j] = MFMA(aU0, frag(O_VR, bcol, kq),     accR[j]);
      accR[j] = MFMA(aU1, frag(O_VR, bcol, 4 + kq), accR[j]);
      accI[j] = MFMA(aU0, frag(O_VI, bcol, kq),     accI[j]);
      accI[j] = MFMA(aU1, frag(O_VI, bcol, 4 + kq), accI[j]);
    }
    #pragma unroll
    for (int j = 0; j < 4; ++j) {
      const int n = 16 * j + (l & 15);
      #pragma unroll
      for (int r = 0; r < 4; ++r) {
        const int c = 16 * wv + (l >> 4) * 4 + r;
        sBr[c * 64 + n] = accR[j][r];
        sBi[c * 64 + n] = accI[j][r];
      }
    }
  }
  __syncthreads();

  if (wv == 0) {
    const float l2r = w16r*w16r - w16i*w16i, l2i = 2.f*w16r*w16i;
    const float lr  = l2r*l2r - l2i*l2i,     li  = 2.f*l2r*l2i;
    float xr = 0.f, xi = 0.f;
    #pragma unroll 4
    for (int c = 0; c < 64; ++c) {
      const int xo = c * 128 + (((l >> 3) ^ (c & 7)) << 4) + (l & 7) * 2;
      *(unsigned short*)(smem + O_XR + xo) = f2h(xr);
      *(unsigned short*)(smem + O_XI + xo) = f2h(xi);
      const float br = sBr[c*64 + l];
      const float bi = sBi[c*64 + l];
      const float nr = fmaf(lr, xr, fmaf(-li, xi, br));
      const float ni = fmaf(lr, xi, fmaf(li, xr, bi));
      xr = nr; xi = ni;
    }
  }
  __syncthreads();

  f32x4 accT[4], accX[4];
  #pragma unroll
  for (int j = 0; j < 4; ++j) { accT[j] = f32x4{0,0,0,0}; accX[j] = f32x4{0,0,0,0}; }
  const s16x8 aXr0 = frag(O_XR, arow, kq);
  const s16x8 aXr1 = frag(O_XR, arow, 4 + kq);
  const s16x8 aXi0 = frag(O_XI, arow, kq);
  const s16x8 aXi1 = frag(O_XI, arow, 4 + kq);
  #pragma unroll
  for (int j = 0; j < 4; ++j) {
    const int bcol = 16 * j + (l & 15);
    accT[j] = MFMA(aU0,  frag(O_TT, bcol, kq),     accT[j]);
    accT[j] = MFMA(aU1,  frag(O_TT, bcol, 4 + kq), accT[j]);
    accX[j] = MFMA(aXr0, frag(O_GR, bcol, kq),     accX[j]);
    accX[j] = MFMA(aXr1, frag(O_GR, bcol, 4 + kq), accX[j]);
    accX[j] = MFMA(aXi0, frag(O_GM, bcol, kq),     accX[j]);
    accX[j] = MFMA(aXi1, frag(O_GM, bcol, 4 + kq), accX[j]);
  }

  const float Dh = Dvec[h];
  const int len = length[b];
  float* yp = y + base;
  #pragma unroll
  for (int j = 0; j < 4; ++j) {
    #pragma unroll
    for (int r = 0; r < 4; ++r) {
      const int t = (16 * wv + (l >> 4) * 4 + r) * 64 + 16 * j + (l & 15);
      const float out = fmaf(Dh, up[t], accT[j][r] + accX[j][r]);
      yp[t] = (t < len) ? out : 0.0f;
    }
  }
}

extern "C" void kernel_launch(void* const* d_in, const int* in_sizes, int n_in,
                              void* d_out, int out_size, void* d_ws, size_t ws_size,
                              hipStream_t stream) {
  const float* u          = (const float*)d_in[0];
  const float* log_dt     = (const float*)d_in[1];
  const float* C          = (const float*)d_in[2];
  const float* log_A_real = (const float*)d_in[3];
  const float* A_imag     = (const float*)d_in[4];
  const float* D          = (const float*)d_in[5];
  const int*   length     = (const int*)d_in[6];
  float* y = (float*)d_out;

  if (ws_size >= WS_NEEDED && d_ws != nullptr) {
    unsigned short* mats = (unsigned short*)d_ws;
    float* lam = (float*)((char*)d_ws + WS_LAM_OFF);
    dssm_setup<<<H_SZ, 256, 0, stream>>>(log_dt, C, log_A_real, A_imag,
                                         mats, lam);
    dssm_main<<<B_SZ * H_SZ, 256, LDS_TOTAL, stream>>>(u, mats, lam, D,
                                                       length, y);
  } else {
    dssm_fb<<<B_SZ * H_SZ, 256, LDS_TOTAL, stream>>>(
        u, log_dt, C, log_A_real, A_imag, D, length, y);
  }
}

// Round 18
// 63.010 us; speedup vs baseline: 10.8822x; 1.0025x over previous
//
#include <hip/hip_runtime.h>

// ROUND 18: byte-for-byte resubmission of round 16's PASSING kernel (63.2 us).
// r17 (NB=4 multi-sequence blocks, X-overlay-B) was the FIFTH structural
// restructure to fail with audit-resistant corruption (r9/r10/r11/r13/r17).
// Locking in the last-known-good design; remaining levers (occupancy via
// LDS-B restructure, cross-iteration pipelining) are in the empirically
// cursed change-class and are abandoned.
//
// Design: two kernels. Setup (1 block/head) builds pre-swizzled fp16 mats
// {Vr,Vi,Tt,Gr,Gm} + fp32 lambda=w^64 in ws. Main (1 block per (b,h)) stages
// mats via linear global_load_lds, computes B=U.V^T (MFMA), serial fp32 scan
// (wave 0) with accT (U.Tt) hidden under it on waves 1-3, then accX (X.G),
// epilogue y = accT + accX + D*u (fp32 u), length-masked.

#define B_SZ 16
#define H_SZ 256
#define L_SZ 4096

using s16x8 = __attribute__((ext_vector_type(8))) short;
using h16x8 = __attribute__((ext_vector_type(8))) _Float16;
using f32x4 = __attribute__((ext_vector_type(4))) float;

template <typename T>
__device__ inline auto mfma_try(T a, T b, f32x4 c, int)
    -> decltype(__builtin_amdgcn_mfma_f32_16x16x32_f16(a, b, c, 0, 0, 0)) {
  return __builtin_amdgcn_mfma_f32_16x16x32_f16(a, b, c, 0, 0, 0);
}
template <typename T>
__device__ inline f32x4 mfma_try(T a, T b, f32x4 c, long) {
  return __builtin_amdgcn_mfma_f32_16x16x32_f16(
      __builtin_bit_cast(h16x8, a), __builtin_bit_cast(h16x8, b), c, 0, 0, 0);
}
__device__ inline f32x4 MFMA(s16x8 a, s16x8 b, f32x4 c) {
  return mfma_try(a, b, c, 0);
}

__device__ inline unsigned short f2h(float f) {
  return __builtin_bit_cast(unsigned short, (_Float16)f);   // RNE
}

// ---- LDS map (80 KB exactly -> 2 blocks/CU) ----
#define O_U   0          // fp16 [64][64] swz
#define O_VR  8192       // fp16 [64][64] swz; dead after B-GEMM -> X real
#define O_VI  16384      // fp16 [64][64] swz; dead after B-GEMM -> X imag
#define O_XR  O_VR
#define O_XI  O_VI
#define O_TT  24576      // fp16 [64][64] swz
#define O_GR  32768      // fp16 [64][64] swz
#define O_GM  40960      // fp16 [64][64] swz
#define O_BR  49152      // f32 [64][64] B real (scan source)
#define O_BI  65536      // f32 [64][64] B imag
#define O_K   O_BR       // (fallback kernel only)
#define LDS_TOTAL 81920

#define MATS_SHORTS_PER_H (5 * 4096)
#define WS_MATS_BYTES ((size_t)H_SZ * MATS_SHORTS_PER_H * 2)       // 10.0 MB
#define WS_LAM_OFF    WS_MATS_BYTES
#define WS_NEEDED     (WS_MATS_BYTES + (size_t)H_SZ * 64 * 2 * 4)  // +128 KB

// ====================== setup: per-head mats, PRE-SWIZZLED ======
__global__ __launch_bounds__(256) void dssm_setup(
    const float* __restrict__ log_dt,
    const float* __restrict__ Cin,
    const float* __restrict__ log_A_real,
    const float* __restrict__ A_imag,
    unsigned short* __restrict__ mats,   // per h: {Vr,Vi,Tt,Gr,Gm}, swizzled
    float* __restrict__ lam)             // per h: 64 x (re,im) of w^64
{
  __shared__ unsigned short sm[5 * 4096];
  __shared__ float sKs[64];
  const int tid = threadIdx.x;
  const int l = tid & 63;
  const int wv = tid >> 6;
  const int h = blockIdx.x;
  char* smb = (char*)sm;

  // ---- per-lane mode params ----
  const float dt = expf(log_dt[h]);
  const float ar = expf(log_A_real[h * 64 + l]);
  const float ai = A_imag[h * 64 + l];
  const float er = expf(-ar * dt);
  const float th = ai * dt;
  const float wr = er * cosf(th), wi = er * sinf(th);
  const float em1r = wr - 1.0f, em1i = wi;
  const float inv = 1.0f / (ar * ar + ai * ai);
  const float qr = (em1i * ai - em1r * ar) * inv;
  const float qi = -(em1r * ai + em1i * ar) * inv;
  const float c0 = Cin[(h * 64 + l) * 2 + 0];
  const float c1 = Cin[(h * 64 + l) * 2 + 1];
  const float c2r = 2.0f * (c0 * qr - c1 * qi);
  const float c2i = 2.0f * (c0 * qi + c1 * qr);

  const float w2r = wr*wr - wi*wi,     w2i = 2.f*wr*wi;
  const float w4r = w2r*w2r - w2i*w2i, w4i = 2.f*w2r*w2i;
  const float w8r = w4r*w4r - w4i*w4i, w8i = 2.f*w4r*w4i;
  const float w16r= w8r*w8r - w8i*w8i, w16i= 2.f*w8r*w8i;

  float b0r = 1.f, b0i = 0.f;                 // w^{16*wv}
  for (int s2 = 0; s2 < wv; ++s2) {
    const float nr = b0r*w16r - b0i*w16i, ni = b0r*w16i + b0i*w16r;
    b0r = nr; b0i = ni;
  }

  // ---- V: V[n=l][63-k] = w^k, SWIZZLED ----
  {
    float pr = b0r, pi = b0i;
    #pragma unroll
    for (int kk = 0; kk < 16; ++kk) {
      const int k = wv * 16 + kk;
      const int c63 = 63 - k;
      const int vb = l * 128 + (((c63 >> 3) ^ (l & 7)) << 4) + (c63 & 7) * 2;
      *(unsigned short*)(smb + 0 * 8192 + vb) = f2h(pr);
      *(unsigned short*)(smb + 1 * 8192 + vb) = f2h(pi);
      const float nr = pr*wr - pi*wi, ni = pr*wi + pi*wr;
      pr = nr; pi = ni;
    }
  }

  // ---- G/K: K[k] -> sKs; G rows SWIZZLED; lam = w^64 (wv==3 tail) ----
  {
    float pr = b0r, pi = b0i;                // w^k
    #pragma unroll
    for (int kk = 0; kk < 16; ++kk) {
      const int k = 16*wv + kk;
      const float gre = c2r*pr - c2i*pi;     // Re(2Ct w^k)
      const float gim = c2r*pi + c2i*pr;
      float s = gre;
      #pragma unroll
      for (int m = 1; m < 64; m <<= 1) s += __shfl_xor(s, m, 64);
      if (l == 0) sKs[k] = s;
      if (k >= 1) {                          // G[k-1][n=l]
        const int row = k - 1;
        const int gb = row * 128 + (((l >> 3) ^ (row & 7)) << 4) + (l & 7) * 2;
        *(unsigned short*)(smb + 3 * 8192 + gb) = f2h(gre);
        *(unsigned short*)(smb + 4 * 8192 + gb) = f2h(-gim);
      }
      const float nr = pr*wr - pi*wi, ni = pr*wi + pi*wr;
      pr = nr; pi = ni;
    }
    if (wv == 3) {                           // k=64: G row 63 + lam
      const float gre = c2r*pr - c2i*pi;
      const float gim = c2r*pi + c2i*pr;
      const int gb = 63 * 128 + (((l >> 3) ^ 7) << 4) + (l & 7) * 2;
      *(unsigned short*)(smb + 3 * 8192 + gb) = f2h(gre);
      *(unsigned short*)(smb + 4 * 8192 + gb) = f2h(-gim);
      lam[(h * 64 + l) * 2 + 0] = pr;        // w^64
      lam[(h * 64 + l) * 2 + 1] = pi;
    }
  }
  __syncthreads();

  // ---- Tt[tau][s] = K[tau-s], SWIZZLED ----
  {
    const int tau = tid >> 2;
    const int sb = tid & 3;
    #pragma unroll
    for (int half = 0; half < 2; ++half) {
      const int q = sb * 2 + half;
      s16x8 v;
      #pragma unroll
      for (int e = 0; e < 8; ++e) {
        const int s = q * 8 + e;
        const float kv = (s <= tau) ? sKs[tau - s] : 0.0f;
        v[e] = (short)f2h(kv);
      }
      *(s16x8*)(smb + 2 * 8192 + tau * 128 + ((q ^ (tau & 7)) << 4)) = v;
    }
  }
  __syncthreads();

  // ---- coalesced copy-out: 2560 chunks of 16 B, 10 per thread ----
  unsigned short* dst = mats + (size_t)h * MATS_SHORTS_PER_H;
  #pragma unroll
  for (int i = 0; i < 10; ++i) {
    const int c = i * 256 + tid;
    *(s16x8*)(dst + c * 8) = *(const s16x8*)(sm + c * 8);
  }
}

// ====================== main: GEMM/scan/epilogue, mats via gload_lds ======
__global__ __launch_bounds__(256) void dssm_main(
    const float* __restrict__ u,
    const unsigned short* __restrict__ mats,
    const float* __restrict__ lam,
    const float* __restrict__ Dvec,
    const int* __restrict__ length,
    float* __restrict__ y)
{
  extern __shared__ char smem[];
  float* sBr = (float*)(smem + O_BR);
  float* sBi = (float*)(smem + O_BI);

  const int tid = threadIdx.x;
  const int l = tid & 63;
  const int wv = tid >> 6;
  const int h = blockIdx.x & 255;
  const int b = blockIdx.x >> 8;
  const size_t base = ((size_t)b * H_SZ + h) * L_SZ;
  const float* up = u + base;

  // early scalar/vector loads
  const float Dh = Dvec[h];
  const int len = length[b];
  const float lr = lam[(h * 64 + l) * 2 + 0];   // w^64 (scan, wave 0)
  const float li = lam[(h * 64 + l) * 2 + 1];

  // ---- phase M: fire-and-forget mats DMA (linear; pre-swizzled in ws) ----
  {
    const unsigned short* mb = mats + (size_t)h * MATS_SHORTS_PER_H;
    for (int g = wv; g < 40; g += 4) {         // 10 issues/wave, 1 KB each
      const unsigned short* src = mb + g * 512 + l * 8;
      __builtin_amdgcn_global_load_lds(
          (const __attribute__((address_space(1))) void*)src,
          (__attribute__((address_space(3))) void*)(smem + 8192 + g * 1024),
          16, 0, 0);
    }
  }

  // ---- phase A: stage U (fp32 -> fp16, XOR-swizzled) ----
  {
    const int e0 = tid * 16;
    const float4 f0 = *(const float4*)(up + e0);
    const float4 f1 = *(const float4*)(up + e0 + 4);
    const float4 f2 = *(const float4*)(up + e0 + 8);
    const float4 f3 = *(const float4*)(up + e0 + 12);
    s16x8 v0, v1;
    v0[0]=(short)f2h(f0.x); v0[1]=(short)f2h(f0.y);
    v0[2]=(short)f2h(f0.z); v0[3]=(short)f2h(f0.w);
    v0[4]=(short)f2h(f1.x); v0[5]=(short)f2h(f1.y);
    v0[6]=(short)f2h(f1.z); v0[7]=(short)f2h(f1.w);
    v1[0]=(short)f2h(f2.x); v1[1]=(short)f2h(f2.y);
    v1[2]=(short)f2h(f2.z); v1[3]=(short)f2h(f2.w);
    v1[4]=(short)f2h(f3.x); v1[5]=(short)f2h(f3.y);
    v1[6]=(short)f2h(f3.z); v1[7]=(short)f2h(f3.w);
    const int r = tid >> 2;
    const int q0 = (2 * tid) & 7;
    char* ub = smem + O_U + r * 128;
    *(s16x8*)(ub + (((q0    ) ^ (r & 7)) << 4)) = v0;
    *(s16x8*)(ub + (((q0 + 1) ^ (r & 7)) << 4)) = v1;
  }
  __syncthreads();                          // sync1: U + all mats visible

  auto frag = [&](int base_, int row, int kc) -> s16x8 {
    return *(const s16x8*)(smem + base_ + row * 128 + ((kc ^ (row & 7)) << 4));
  };
  const int arow = 16 * wv + (l & 15);
  const int kq = l >> 4;
  const s16x8 aU0 = frag(O_U, arow, kq);
  const s16x8 aU1 = frag(O_U, arow, 4 + kq);

  // ---- B-GEMM: B = U.V^T via MFMA, B written fp32 ----
  {
    f32x4 accR[4], accI[4];
    #pragma unroll
    for (int j = 0; j < 4; ++j) { accR[j] = f32x4{0,0,0,0}; accI[j] = f32x4{0,0,0,0}; }
    #pragma unroll
    for (int j = 0; j < 4; ++j) {
      const int bcol = 16 * j + (l & 15);
      accR[j] = MFMA(aU0, frag(O_VR, bcol, kq),     accR[j]);
      accR[j] = MFMA(aU1, frag(O_VR, bcol, 4 + kq), accR[j]);
      accI[j] = MFMA(aU0, frag(O_VI, bcol, kq),     accI[j]);
      accI[j] = MFMA(aU1, frag(O_VI, bcol, 4 + kq), accI[j]);
    }
    #pragma unroll
    for (int j = 0; j < 4; ++j) {
      const int n = 16 * j + (l & 15);
      #pragma unroll
      for (int r = 0; r < 4; ++r) {
        const int c = 16 * wv + (l >> 4) * 4 + r;
        sBr[c * 64 + n] = accR[j][r];
        sBi[c * 64 + n] = accI[j][r];
      }
    }
  }
  __syncthreads();                          // sync2: B complete; V dead

  // ---- scan slot: wave 0 scans; waves 1-3 run accT (U.Tt, X-independent) ----
  f32x4 accT[4];
  #pragma unroll
  for (int j = 0; j < 4; ++j) accT[j] = f32x4{0,0,0,0};
  auto do_accT = [&]() {
    #pragma unroll
    for (int j = 0; j < 4; ++j) {
      const int bcol = 16 * j + (l & 15);
      accT[j] = MFMA(aU0, frag(O_TT, bcol, kq),     accT[j]);
      accT[j] = MFMA(aU1, frag(O_TT, bcol, 4 + kq), accT[j]);
    }
  };
  if (wv == 0) {
    // fp32 serial scan, X fp16 swz into dead V region
    float xr = 0.f, xi = 0.f;
    #pragma unroll 4
    for (int c = 0; c < 64; ++c) {
      const int xo = c * 128 + (((l >> 3) ^ (c & 7)) << 4) + (l & 7) * 2;
      *(unsigned short*)(smem + O_XR + xo) = f2h(xr);
      *(unsigned short*)(smem + O_XI + xo) = f2h(xi);
      const float br = sBr[c*64 + l];
      const float bi = sBi[c*64 + l];
      const float nr = fmaf(lr, xr, fmaf(-li, xi, br));
      const float ni = fmaf(lr, xi, fmaf(li, xr, bi));
      xr = nr; xi = ni;
    }
  } else {
    do_accT();                              // reads O_TT only: disjoint
  }
  __syncthreads();                          // sync3: X visible

  // ---- epilogue u prefetch (issue-early, consume-late) ----
  float ureg[16];
  #pragma unroll
  for (int j = 0; j < 4; ++j) {
    #pragma unroll
    for (int r = 0; r < 4; ++r) {
      ureg[j * 4 + r] = up[(16 * wv + (l >> 4) * 4 + r) * 64 + 16 * j + (l & 15)];
    }
  }

  if (wv == 0) do_accT();                   // wave 0's accT (TT still stable)

  // ---- accX: X.G via MFMA ----
  f32x4 accX[4];
  #pragma unroll
  for (int j = 0; j < 4; ++j) accX[j] = f32x4{0,0,0,0};
  const s16x8 aXr0 = frag(O_XR, arow, kq);
  const s16x8 aXr1 = frag(O_XR, arow, 4 + kq);
  const s16x8 aXi0 = frag(O_XI, arow, kq);
  const s16x8 aXi1 = frag(O_XI, arow, 4 + kq);
  #pragma unroll
  for (int j = 0; j < 4; ++j) {
    const int bcol = 16 * j + (l & 15);
    accX[j] = MFMA(aXr0, frag(O_GR, bcol, kq),     accX[j]);
    accX[j] = MFMA(aXr1, frag(O_GR, bcol, 4 + kq), accX[j]);
    accX[j] = MFMA(aXi0, frag(O_GM, bcol, kq),     accX[j]);
    accX[j] = MFMA(aXi1, frag(O_GM, bcol, 4 + kq), accX[j]);
  }

  // ---- epilogue: y = accT + accX + D*u (fp32), length mask ----
  float* yp = y + base;
  #pragma unroll
  for (int j = 0; j < 4; ++j) {
    #pragma unroll
    for (int r = 0; r < 4; ++r) {
      const int t = (16 * wv + (l >> 4) * 4 + r) * 64 + 16 * j + (l & 15);
      const float out = fmaf(Dh, ureg[j * 4 + r], accT[j][r] + accX[j][r]);
      yp[t] = (t < len) ? out : 0.0f;
    }
  }
}

// ====================== fallback: r14 single kernel (ws too small) ======
__global__ __launch_bounds__(256) void dssm_fb(
    const float* __restrict__ u,
    const float* __restrict__ log_dt,
    const float* __restrict__ Cin,
    const float* __restrict__ log_A_real,
    const float* __restrict__ A_imag,
    const float* __restrict__ Dvec,
    const int* __restrict__ length,
    float* __restrict__ y)
{
  extern __shared__ char smem[];
  float* sBr = (float*)(smem + O_BR);
  float* sBi = (float*)(smem + O_BI);
  float* sK  = (float*)(smem + O_K);

  const int tid = threadIdx.x;
  const int l = tid & 63;
  const int wv = tid >> 6;
  const int h = blockIdx.x & 255;
  const int b = blockIdx.x >> 8;
  const size_t base = ((size_t)b * H_SZ + h) * L_SZ;
  const float* up = u + base;

  const float dt = expf(log_dt[h]);
  const float ar = expf(log_A_real[h * 64 + l]);
  const float ai = A_imag[h * 64 + l];
  const float er = expf(-ar * dt);
  const float th = ai * dt;
  const float wr = er * cosf(th), wi = er * sinf(th);
  const float em1r = wr - 1.0f, em1i = wi;
  const float inv = 1.0f / (ar * ar + ai * ai);
  const float qr = (em1i * ai - em1r * ar) * inv;
  const float qi = -(em1r * ai + em1i * ar) * inv;
  const float c0 = Cin[(h * 64 + l) * 2 + 0];
  const float c1 = Cin[(h * 64 + l) * 2 + 1];
  const float c2r = 2.0f * (c0 * qr - c1 * qi);
  const float c2i = 2.0f * (c0 * qi + c1 * qr);

  const float w2r = wr*wr - wi*wi,     w2i = 2.f*wr*wi;
  const float w4r = w2r*w2r - w2i*w2i, w4i = 2.f*w2r*w2i;
  const float w8r = w4r*w4r - w4i*w4i, w8i = 2.f*w4r*w4i;
  const float w16r= w8r*w8r - w8i*w8i, w16i= 2.f*w8r*w8i;

  float b0r = 1.f, b0i = 0.f;
  for (int s2 = 0; s2 < wv; ++s2) {
    const float nr = b0r*w16r - b0i*w16i, ni = b0r*w16i + b0i*w16r;
    b0r = nr; b0i = ni;
  }

  {
    const int e0 = tid * 16;
    const float4 f0 = *(const float4*)(up + e0);
    const float4 f1 = *(const float4*)(up + e0 + 4);
    const float4 f2 = *(const float4*)(up + e0 + 8);
    const float4 f3 = *(const float4*)(up + e0 + 12);
    s16x8 v0, v1;
    v0[0]=(short)f2h(f0.x); v0[1]=(short)f2h(f0.y);
    v0[2]=(short)f2h(f0.z); v0[3]=(short)f2h(f0.w);
    v0[4]=(short)f2h(f1.x); v0[5]=(short)f2h(f1.y);
    v0[6]=(short)f2h(f1.z); v0[7]=(short)f2h(f1.w);
    v1[0]=(short)f2h(f2.x); v1[1]=(short)f2h(f2.y);
    v1[2]=(short)f2h(f2.z); v1[3]=(short)f2h(f2.w);
    v1[4]=(short)f2h(f3.x); v1[5]=(short)f2h(f3.y);
    v1[6]=(short)f2h(f3.z); v1[7]=(short)f2h(f3.w);
    const int r = tid >> 2;
    const int q0 = (2 * tid) & 7;
    char* ub = smem + O_U + r * 128;
    *(s16x8*)(ub + (((q0    ) ^ (r & 7)) << 4)) = v0;
    *(s16x8*)(ub + (((q0 + 1) ^ (r & 7)) << 4)) = v1;
  }
  {
    float pr = b0r, pi = b0i;
    #pragma unroll
    for (int kk = 0; kk < 16; ++kk) {
      const int k = wv * 16 + kk;
      const int c63 = 63 - k;
      const int vb = l * 128 + (((c63 >> 3) ^ (l & 7)) << 4) + (c63 & 7) * 2;
      *(unsigned short*)(smem + O_VR + vb) = f2h(pr);
      *(unsigned short*)(smem + O_VI + vb) = f2h(pi);
      const float nr = pr*wr - pi*wi, ni = pr*wi + pi*wr;
      pr = nr; pi = ni;
    }
  }
  {
    float pr = b0r, pi = b0i;
    #pragma unroll
    for (int kk = 0; kk < 16; ++kk) {
      const int k = 16*wv + kk;
      const float gre = c2r*pr - c2i*pi;
      const float gim = c2r*pi + c2i*pr;
      float s = gre;
      #pragma unroll
      for (int m = 1; m < 64; m <<= 1) s += __shfl_xor(s, m, 64);
      if (l == 0) sK[k] = s;
      if (k >= 1) {
        const int row = k - 1;
        const int gb = row * 128 + (((l >> 3) ^ (row & 7)) << 4) + (l & 7) * 2;
        *(unsigned short*)(smem + O_GR + gb) = f2h(gre);
        *(unsigned short*)(smem + O_GM + gb) = f2h(-gim);
      }
      const float nr = pr*wr - pi*wi, ni = pr*wi + pi*wr;
      pr = nr; pi = ni;
    }
    if (wv == 3) {
      const float gre = c2r*pr - c2i*pi;
      const float gim = c2r*pi + c2i*pr;
      const int gb = 63 * 128 + (((l >> 3) ^ 7) << 4) + (l & 7) * 2;
      *(unsigned short*)(smem + O_GR + gb) = f2h(gre);
      *(unsigned short*)(smem + O_GM + gb) = f2h(-gim);
    }
  }
  __syncthreads();
  {
    const int tau = tid >> 2;
    const int sb = tid & 3;
    #pragma unroll
    for (int half = 0; half < 2; ++half) {
      const int q = sb * 2 + half;
      s16x8 v;
      #pragma unroll
      for (int e = 0; e < 8; ++e) {
        const int s = q * 8 + e;
        float kv = 0.0f;
        if (s <= tau) kv = sK[tau - s];
        v[e] = (short)f2h(kv);
      }
      *(s16x8*)(smem + O_TT + tau * 128 + ((q ^ (tau & 7)) << 4)) = v;
    }
  }
  __syncthreads();

  auto frag = [&](int base_, int row, int kc) -> s16x8 {
    return *(const s16x8*)(smem + base_ + row * 128 + ((kc ^ (row & 7)) << 4));
  };
  const int arow = 16 * wv + (l & 15);
  const int kq = l >> 4;
  const s16x8 aU0 = frag(O_U, arow, kq);
  const s16x8 aU1 = frag(O_U, arow, 4 + kq);

  {
    f32x4 accR[4], accI[4];
    #pragma unroll
    for (int j = 0; j < 4; ++j) { accR[j] = f32x4{0,0,0,0}; accI[j] = f32x4{0,0,0,0}; }
    #pragma unroll
    for (int j = 0; j < 4; ++j) {
      const int bcol = 16 * j + (l & 15);
      accR[j] = MFMA(aU0, frag(O_VR, bcol, kq),     accR[j]);
      accR[j] = MFMA(aU1, frag(O_VR, bcol, 4 + kq), accR[j]);
      accI[j] = MFMA(aU0, frag(O_VI, bcol, kq),     accI[j]);
      accI[j] = MFMA(aU1, frag(O_VI, bcol, 4 + kq), accI[j]);
    }
    #pragma unroll
    for (int j = 0; j < 4; ++j) {
      const int n = 16 * j + (l & 15);
      #pragma unroll
      for (int r = 0; r < 4; ++r) {
        const int c = 16 * wv + (l >> 4) * 4 + r;
        sBr[c * 64 + n] = accR[j][r];
        sBi[c * 64 + n] = accI[j][r];
      }
    }
  }
  __syncthreads();

  if (wv == 0) {
    const float l2r = w16r*w16r - w16i*w16i, l2i = 2.f*w16r*w16i;
    const float lr  = l2r*l2r - l2i*l2i,     li  = 2.f*l2r*l2i;
    float xr = 0.f, xi = 0.f;
    #pragma unroll 4
    for (int c = 0; c < 64; ++c) {
      const int xo = c * 128 + (((l >> 3) ^ (c & 7)) << 4) + (l & 7) * 2;
      *(unsigned short*)(smem + O_XR + xo) = f2h(xr);
      *(unsigned short*)(smem + O_XI + xo) = f2h(xi);
      const float br = sBr[c*64 + l];
      const float bi = sBi[c*64 + l];
      const float nr = fmaf(lr, xr, fmaf(-li, xi, br));
      const float ni = fmaf(lr, xi, fmaf(li, xr, bi));
      xr = nr; xi = ni;
    }
  }
  __syncthreads();

  f32x4 accT[4], accX[4];
  #pragma unroll
  for (int j = 0; j < 4; ++j) { accT[j] = f32x4{0,0,0,0}; accX[j] = f32x4{0,0,0,0}; }
  const s16x8 aXr0 = frag(O_XR, arow, kq);
  const s16x8 aXr1 = frag(O_XR, arow, 4 + kq);
  const s16x8 aXi0 = frag(O_XI, arow, kq);
  const s16x8 aXi1 = frag(O_XI, arow, 4 + kq);
  #pragma unroll
  for (int j = 0; j < 4; ++j) {
    const int bcol = 16 * j + (l & 15);
    accT[j] = MFMA(aU0,  frag(O_TT, bcol, kq),     accT[j]);
    accT[j] = MFMA(aU1,  frag(O_TT, bcol, 4 + kq), accT[j]);
    accX[j] = MFMA(aXr0, frag(O_GR, bcol, kq),     accX[j]);
    accX[j] = MFMA(aXr1, frag(O_GR, bcol, 4 + kq), accX[j]);
    accX[j] = MFMA(aXi0, frag(O_GM, bcol, kq),     accX[j]);
    accX[j] = MFMA(aXi1, frag(O_GM, bcol, 4 + kq), accX[j]);
  }

  const float Dh = Dvec[h];
  const int len = length[b];
  float* yp = y + base;
  #pragma unroll
  for (int j = 0; j < 4; ++j) {
    #pragma unroll
    for (int r = 0; r < 4; ++r) {
      const int t = (16 * wv + (l >> 4) * 4 + r) * 64 + 16 * j + (l & 15);
      const float out = fmaf(Dh, up[t], accT[j][r] + accX[j][r]);
      yp[t] = (t < len) ? out : 0.0f;
    }
  }
}

extern "C" void kernel_launch(void* const* d_in, const int* in_sizes, int n_in,
                              void* d_out, int out_size, void* d_ws, size_t ws_size,
                              hipStream_t stream) {
  const float* u          = (const float*)d_in[0];
  const float* log_dt     = (const float*)d_in[1];
  const float* C          = (const float*)d_in[2];
  const float* log_A_real = (const float*)d_in[3];
  const float* A_imag     = (const float*)d_in[4];
  const float* D          = (const float*)d_in[5];
  const int*   length     = (const int*)d_in[6];
  float* y = (float*)d_out;

  if (ws_size >= WS_NEEDED && d_ws != nullptr) {
    unsigned short* mats = (unsigned short*)d_ws;
    float* lam = (float*)((char*)d_ws + WS_LAM_OFF);
    dssm_setup<<<H_SZ, 256, 0, stream>>>(log_dt, C, log_A_real, A_imag,
                                         mats, lam);
    dssm_main<<<B_SZ * H_SZ, 256, LDS_TOTAL, stream>>>(u, mats, lam, D,
                                                       length, y);
  } else {
    dssm_fb<<<B_SZ * H_SZ, 256, LDS_TOTAL, stream>>>(
        u, log_dt, C, log_A_real, A_imag, D, length, y);
  }
}